// Round 6
// baseline (1106.765 us; speedup 1.0000x reference)
//
#include <hip/hip_runtime.h>
#include <math.h>
#include <stdint.h>

typedef __bf16 bf16;
typedef __bf16 bf16x8 __attribute__((ext_vector_type(8)));
typedef __bf16 bf16x4 __attribute__((ext_vector_type(4)));
typedef float f32x4 __attribute__((ext_vector_type(4)));

#define DEV __device__ __forceinline__

// async global->LDS, 16B per lane. LDS dest must be wave-uniform base + lane*16.
DEV void g2l16(void* lds, const void* g) {
    __builtin_amdgcn_global_load_lds(
        (const __attribute__((address_space(1))) uint32_t*)g,
        (__attribute__((address_space(3))) uint32_t*)lds,
        16, 0, 0);
}

// Fast gelu: x * sigmoid(1.5957691216*(x + 0.044715 x^3)).
DEV float gelu_fast(float x) {
    float u = -1.5957691216f * __builtin_fmaf(0.044715f * x, x * x, x);
    return x * __builtin_amdgcn_rcpf(1.f + __expf(u));
}

// XCD-chunked block swizzle (T1): each XCD gets a contiguous chunk of tiles
// so consecutive blocks on one XCD share operand panels in its private L2.
// Bijective iff nwg % 8 == 0 (guarded). Measured r5: W2 FETCH -33%, -8% dur.
DEV void xcd_swizzle(int& bx, int& by, int& bz) {
    int gx = gridDim.x, gy = gridDim.y, gz = gridDim.z;
    int nwg = gx * gy * gz;
    if (nwg & 7) return;
    long flat = ((long)bz * gy + by) * gx + bx;
    long q = nwg >> 3;
    long sw = (flat & 7) * q + (flat >> 3);
    bx = (int)(sw % gx);
    long t = sw / gx;
    by = (int)(t % gy);
    bz = (int)(t / gy);
}

// ---------------------------------------------------------------------------
// Generic bf16 GEMM: C = alpha * A @ Bt^T. 128x128 tile, BK=64, 256 threads =
// 4 waves (2x2), each wave 64x64 via 4x4 mfma_f32_16x16x32_bf16. LDS
// k-chunked [kc][row][8]: conflict-free ds_read_b128, g2l16 staging.
// m97 structure: needs >=4 blocks/CU of TLP to hide the barrier drain
// (m103: 912 TF at grid 1024/K=4096; our r5 W2 at grid 512 = 2/CU: 497 TF).
// Split-K is expressed through the existing z-batching (sAi/sBi = K-offset,
// sCi = partial-buffer stride) -> grid gains a z=2 dim, 4 blocks/CU.
// ---------------------------------------------------------------------------
template <int EPI, typename TC>
__global__ __launch_bounds__(256)
void gemm_bt(const bf16* __restrict__ A, const bf16* __restrict__ Bt, TC* __restrict__ C,
             int K, int lda, int ldb, int ldc,
             long sAo, long sAi, long sBo, long sBi, long sCo, long sCi, int zInner,
             float alpha)
{
    int bx = blockIdx.x, by = blockIdx.y, bz = blockIdx.z;
    xcd_swizzle(bx, by, bz);

    int zo = bz / zInner, zi = bz % zInner;
    A  += (long)zo * sAo + (long)zi * sAi;
    Bt += (long)zo * sBo + (long)zi * sBi;
    long cOff = (long)zo * sCo + (long)zi * sCi;

    int tileN = bx * 128, tileM = by * 128;

    __shared__ bf16 As[8192];  // [kc][row][8]
    __shared__ bf16 Bs[8192];

    int tid = threadIdx.x;
    int wave = tid >> 6, lane = tid & 63, quad = lane >> 4, l15 = lane & 15;
    int wm = (wave >> 1) * 64, wn = (wave & 1) * 64;

    f32x4 acc[4][4] = {};

    for (int k0 = 0; k0 < K; k0 += 64) {
#pragma unroll
        for (int r = 0; r < 4; ++r) {
            int c = r * 256 + tid;
            int kc = c >> 7, row = c & 127;
            g2l16(&As[c * 8], A + (long)(tileM + row) * lda + (k0 + kc * 8));
            g2l16(&Bs[c * 8], Bt + (long)(tileN + row) * ldb + (k0 + kc * 8));
        }
        __syncthreads();
#pragma unroll
        for (int ks = 0; ks < 2; ++ks) {
            bf16x8 af[4], bq[4];
#pragma unroll
            for (int i = 0; i < 4; ++i) {
                af[i] = *(const bf16x8*)&As[((ks * 4 + quad) * 128 + wm + i * 16 + l15) * 8];
                bq[i] = *(const bf16x8*)&Bs[((ks * 4 + quad) * 128 + wn + i * 16 + l15) * 8];
            }
#pragma unroll
            for (int mi = 0; mi < 4; ++mi)
#pragma unroll
                for (int ni = 0; ni < 4; ++ni)
                    acc[mi][ni] = __builtin_amdgcn_mfma_f32_16x16x32_bf16(
                        af[mi], bq[ni], acc[mi][ni], 0, 0, 0);
        }
        __syncthreads();
    }

#pragma unroll
    for (int mi = 0; mi < 4; ++mi) {
#pragma unroll
        for (int r = 0; r < 4; ++r) {
            int gm = tileM + wm + mi * 16 + quad * 4 + r;
#pragma unroll
            for (int ni = 0; ni < 4; ++ni) {
                int gn = tileN + wn + ni * 16 + l15;
                C[cOff + (long)gm * ldc + gn] = (TC)(acc[mi][ni][r] * alpha);
            }
        }
    }
}

// ---------------------------------------------------------------------------
// Deep-pipelined 256x256 GEMM for h1: C = gelu(A @ Bt^T + bias), bf16 out.
// BK=32, 3-deep LDS ring (96KB), counted vmcnt(8). Measured ~680 TF (r2/r5).
// ---------------------------------------------------------------------------
__global__ __launch_bounds__(512, 2)
void gemm256_h1(const bf16* __restrict__ A, const bf16* __restrict__ Bt,
                bf16* __restrict__ C, int K, int lda, int ldb, int ldc,
                const float* __restrict__ bias)
{
    __shared__ bf16 lds[3][2][8192];   // [buf][A/B][kc*256+row][8] 16KB each

    int bx = blockIdx.x, by = blockIdx.y, bz = blockIdx.z;
    xcd_swizzle(bx, by, bz);

    int tid = threadIdx.x;
    int wave = tid >> 6, lane = tid & 63, quad = lane >> 4, l15 = lane & 15;
    int wm = (wave >> 2) * 128, wn = (wave & 3) * 64;
    int tileN = bx * 256, tileM = by * 256;

    int c0 = tid, c1 = 512 + tid;
    int kc0 = c0 >> 8, row0 = c0 & 255;
    int kc1 = c1 >> 8, row1 = c1 & 255;
    const bf16* A0 = A + (long)(tileM + row0) * lda + kc0 * 8;
    const bf16* A1 = A + (long)(tileM + row1) * lda + kc1 * 8;
    const bf16* B0 = Bt + (long)(tileN + row0) * ldb + kc0 * 8;
    const bf16* B1 = Bt + (long)(tileN + row1) * ldb + kc1 * 8;

    f32x4 acc[8][4] = {};

    int aoff = (quad * 256 + wm + l15) * 8;
    int boff = (quad * 256 + wn + l15) * 8;

    auto stage = [&](int t, int b) {
        int k0 = t * 32;
        g2l16(&lds[b][0][c0 * 8], A0 + k0);
        g2l16(&lds[b][0][c1 * 8], A1 + k0);
        g2l16(&lds[b][1][c0 * 8], B0 + k0);
        g2l16(&lds[b][1][c1 * 8], B1 + k0);
    };

    stage(0, 0);
    stage(1, 1);

    int T = K >> 5;
    int cb = 0;
    for (int t = 0; t < T; ++t) {
        int nb = cb + 2; if (nb >= 3) nb -= 3;
        stage(t + 2, nb);   // garbage for t >= T-2; never consumed (in-ws reads)

        asm volatile("s_waitcnt vmcnt(8)\n\ts_barrier" ::: "memory");

        const bf16* pA = &lds[cb][0][0];
        const bf16* pB = &lds[cb][1][0];
        bf16x8 af[8], bq[4];
#pragma unroll
        for (int mi = 0; mi < 8; ++mi)
            af[mi] = *(const bf16x8*)&pA[aoff + mi * 128];
#pragma unroll
        for (int ni = 0; ni < 4; ++ni)
            bq[ni] = *(const bf16x8*)&pB[boff + ni * 128];

        __builtin_amdgcn_s_setprio(1);
#pragma unroll
        for (int mi = 0; mi < 8; ++mi)
#pragma unroll
            for (int ni = 0; ni < 4; ++ni)
                acc[mi][ni] = __builtin_amdgcn_mfma_f32_16x16x32_bf16(
                    af[mi], bq[ni], acc[mi][ni], 0, 0, 0);
        __builtin_amdgcn_s_setprio(0);

        asm volatile("s_barrier" ::: "memory");
        cb = (cb == 2) ? 0 : cb + 1;
    }

    float bb[4];
#pragma unroll
    for (int ni = 0; ni < 4; ++ni)
        bb[ni] = bias[tileN + wn + ni * 16 + l15];

#pragma unroll
    for (int mi = 0; mi < 8; ++mi) {
#pragma unroll
        for (int r = 0; r < 4; ++r) {
            int gm = tileM + wm + mi * 16 + quad * 4 + r;
#pragma unroll
            for (int ni = 0; ni < 4; ++ni) {
                int gn = tileN + wn + ni * 16 + l15;
                float x = acc[mi][ni][r] + bb[ni];
                C[(long)gm * ldc + gn] = (bf16)gelu_fast(x);
            }
        }
    }
}

// ---------------------------------------------------------------------------
// Split-K reduce kernels. Partials are bf16 (rounding error ~0.003 on the
// partial, x0.0997 gate or 0.088 scale downstream -> ~3e-4 in outputs).
// ---------------------------------------------------------------------------
// q = p0 + p1 (bf16 out). 8 elems/thread.
__global__ __launch_bounds__(256)
void reduce_q(const bf16* __restrict__ p0, const bf16* __restrict__ p1,
              bf16* __restrict__ out)
{
    long e = ((long)blockIdx.x * 256 + threadIdx.x) * 8;
    bf16x8 a = *(const bf16x8*)(p0 + e);
    bf16x8 b = *(const bf16x8*)(p1 + e);
    bf16x8 o;
#pragma unroll
    for (int j = 0; j < 8; ++j) o[j] = (bf16)((float)a[j] + (float)b[j]);
    *(bf16x8*)(out + e) = o;
}

// x2 = hidden + tanh(ga)*(p0+p1)*mask[row] (f32 out). row = e>>11.
__global__ __launch_bounds__(256)
void reduce_wo(const bf16* __restrict__ p0, const bf16* __restrict__ p1,
               const float* __restrict__ hidden, const float* __restrict__ ga,
               const int* __restrict__ media, float* __restrict__ x2)
{
    long e = ((long)blockIdx.x * 256 + threadIdx.x) * 8;
    float g = tanhf(ga[0]) * (media[e >> 11] ? 1.f : 0.f);
    bf16x8 a = *(const bf16x8*)(p0 + e);
    bf16x8 b = *(const bf16x8*)(p1 + e);
    float4 h0 = *(const float4*)(hidden + e);
    float4 h1 = *(const float4*)(hidden + e + 4);
    float h[8] = {h0.x, h0.y, h0.z, h0.w, h1.x, h1.y, h1.z, h1.w};
    float o[8];
#pragma unroll
    for (int j = 0; j < 8; ++j)
        o[j] = h[j] + g * ((float)a[j] + (float)b[j]);
    *(float4*)(x2 + e)     = make_float4(o[0], o[1], o[2], o[3]);
    *(float4*)(x2 + e + 4) = make_float4(o[4], o[5], o[6], o[7]);
}

// out = x2 + tanh(gf)*(p0+p1+b2[col]) (f32 out). col = e & 2047.
__global__ __launch_bounds__(256)
void reduce_w2(const bf16* __restrict__ p0, const bf16* __restrict__ p1,
               const float* __restrict__ x2, const float* __restrict__ b2,
               const float* __restrict__ gf, float* __restrict__ out)
{
    long e = ((long)blockIdx.x * 256 + threadIdx.x) * 8;
    float g = tanhf(gf[0]);
    int col = (int)(e & 2047);
    bf16x8 a = *(const bf16x8*)(p0 + e);
    bf16x8 b = *(const bf16x8*)(p1 + e);
    float4 x0 = *(const float4*)(x2 + e);
    float4 x1 = *(const float4*)(x2 + e + 4);
    float4 c0 = *(const float4*)(b2 + col);
    float4 c1 = *(const float4*)(b2 + col + 4);
    float x[8] = {x0.x, x0.y, x0.z, x0.w, x1.x, x1.y, x1.z, x1.w};
    float c[8] = {c0.x, c0.y, c0.z, c0.w, c1.x, c1.y, c1.z, c1.w};
    float o[8];
#pragma unroll
    for (int j = 0; j < 8; ++j)
        o[j] = x[j] + g * ((float)a[j] + (float)b[j] + c[j]);
    *(float4*)(out + e)     = make_float4(o[0], o[1], o[2], o[3]);
    *(float4*)(out + e + 4) = make_float4(o[4], o[5], o[6], o[7]);
}

// ---------------------------------------------------------------------------
// LayerNorm over rows of 2048 (f32 in, f32 params, bf16 out). One row/block.
// ---------------------------------------------------------------------------
__global__ __launch_bounds__(256)
void ln_k(const float* __restrict__ x, const float* __restrict__ g, const float* __restrict__ b,
          bf16* __restrict__ out)
{
    long row = blockIdx.x;
    int tid = threadIdx.x;
    int wave = tid >> 6, lane = tid & 63;
    const float* px = x + row * 2048 + tid * 8;

    float4 a = *(const float4*)px;
    float4 c = *(const float4*)(px + 4);
    float f[8] = {a.x, a.y, a.z, a.w, c.x, c.y, c.z, c.w};

    float s = 0.f, s2 = 0.f;
#pragma unroll
    for (int j = 0; j < 8; ++j) { s += f[j]; s2 += f[j] * f[j]; }
    for (int o = 32; o; o >>= 1) { s += __shfl_xor(s, o, 64); s2 += __shfl_xor(s2, o, 64); }

    __shared__ float red[8];
    if (lane == 0) { red[wave] = s; red[4 + wave] = s2; }
    __syncthreads();
    s  = red[0] + red[1] + red[2] + red[3];
    s2 = red[4] + red[5] + red[6] + red[7];

    float mean = s * (1.f / 2048.f);
    float var  = s2 * (1.f / 2048.f) - mean * mean;
    float rstd = rsqrtf(var + 1e-5f);

    int col = tid * 8;
    bf16x8 o8;
#pragma unroll
    for (int j = 0; j < 8; ++j)
        o8[j] = (bf16)((f[j] - mean) * rstd * g[col + j] + b[col + j]);
    *(bf16x8*)(out + row * 2048 + tid * 8) = o8;
}

// ---------------------------------------------------------------------------
// Row softmax over 512 (in-place, bf16). One wave per row, 4 rows per block.
// ---------------------------------------------------------------------------
__global__ __launch_bounds__(256)
void softmax512(bf16* __restrict__ s)
{
    long row = (long)blockIdx.x * 4 + (threadIdx.x >> 6);
    int lane = threadIdx.x & 63;
    bf16* p = s + row * 512 + lane * 8;
    bf16x8 v = *(const bf16x8*)p;
    float f[8], mx = -1e30f;
#pragma unroll
    for (int j = 0; j < 8; ++j) { f[j] = (float)v[j]; mx = fmaxf(mx, f[j]); }
    for (int o = 32; o; o >>= 1) mx = fmaxf(mx, __shfl_xor(mx, o, 64));
    float sum = 0.f;
#pragma unroll
    for (int j = 0; j < 8; ++j) { f[j] = __expf(f[j] - mx); sum += f[j]; }
    for (int o = 32; o; o >>= 1) sum += __shfl_xor(sum, o, 64);
    float r = 1.f / sum;
    bf16x8 o8;
#pragma unroll
    for (int j = 0; j < 8; ++j) o8[j] = (bf16)(f[j] * r);
    *(bf16x8*)p = o8;
}

// ---------------------------------------------------------------------------
// Transpose f32 -> bf16: out[n][m] = (bf16)in[m][n]. Tile 64m x 32n, 256 thr.
// Write side: bf16x4 per store -> 128B contiguous per 16 lanes (2x the old
// 32x32 version's write width). LDS pad 33 keeps reads ~conflict-free.
// ---------------------------------------------------------------------------
__global__ __launch_bounds__(256)
void transpose_cvt(const float* __restrict__ in, bf16* __restrict__ out, int ldi, int ldo)
{
    __shared__ float t[64][33];
    int tx = threadIdx.x & 31, ty = threadIdx.x >> 5;
    int n0 = blockIdx.x * 32, m0 = blockIdx.y * 64;
#pragma unroll
    for (int i = 0; i < 8; ++i)
        t[ty + i * 8][tx] = in[(long)(m0 + ty + i * 8) * ldi + n0 + tx];
    __syncthreads();
    int wx = threadIdx.x & 15, wy = threadIdx.x >> 4;
#pragma unroll
    for (int j = 0; j < 2; ++j) {
        int n = wy + j * 16;
        bf16x4 v;
        v[0] = (bf16)t[4 * wx + 0][n];
        v[1] = (bf16)t[4 * wx + 1][n];
        v[2] = (bf16)t[4 * wx + 2][n];
        v[3] = (bf16)t[4 * wx + 3][n];
        *(bf16x4*)(out + (long)(n0 + n) * ldo + m0 + 4 * wx) = v;
    }
}

// ---------------------------------------------------------------------------
// Batched bf16 transpose (for V): out[n][m] = in[m][n]. Tile 32x32.
// ---------------------------------------------------------------------------
__global__ __launch_bounds__(256)
void transpose_k(const bf16* __restrict__ in, bf16* __restrict__ out,
                 int ldi, int ldo, long sIo, long sIi, long sOo, long sOi, int zInner)
{
    int z = blockIdx.z;
    in  += (long)(z / zInner) * sIo + (long)(z % zInner) * sIi;
    out += (long)(z / zInner) * sOo + (long)(z % zInner) * sOi;
    __shared__ bf16 t[32][33];
    int tx = threadIdx.x & 31, ty = threadIdx.x >> 5;
    int n0 = blockIdx.x * 32, m0 = blockIdx.y * 32;
#pragma unroll
    for (int i = 0; i < 4; ++i)
        t[ty + i * 8][tx] = in[(long)(m0 + ty + i * 8) * ldi + n0 + tx];
    __syncthreads();
#pragma unroll
    for (int i = 0; i < 4; ++i)
        out[(long)(n0 + ty + i * 8) * ldo + m0 + tx] = t[tx][ty + i * 8];
}

// f32 -> bf16 elementwise (for image_embeds). 4 elems/thread.
__global__ __launch_bounds__(256)
void cvt_k(const float* __restrict__ in, bf16* __restrict__ out)
{
    int i = (blockIdx.x * 256 + threadIdx.x) * 4;
    float4 v = *(const float4*)(in + i);
    out[i + 0] = (bf16)v.x;
    out[i + 1] = (bf16)v.y;
    out[i + 2] = (bf16)v.z;
    out[i + 3] = (bf16)v.w;
}

// ---------------------------------------------------------------------------
// Workspace layout (MiB offsets), peak 176 MiB:
//   0-32   : WqT(0) WkT(8) WvT(16) WoT(24) -> W1T(0-32) -> W2 partials(0-32)
//   32-48  : xln        -> later W2T low half
//   48-64  : q/attn_out -> later W2T high half
//   64-68  : kbuf   68-72: vbuf   72-76: vt   76-80: imgb
//   80-144 : q/Wo partials (80-112) -> sc (scores -> P) -> h1
//   144-176: x2 (f32)
// Partial lifetime checks: q partials (80-112) consumed by reduce_q before
// scores writes sc@80+; Wo partials (80-112) written after PV consumed P;
// W2 partials (0-32) written after h1 (W1T dead).
// ---------------------------------------------------------------------------
extern "C" void kernel_launch(void* const* d_in, const int* in_sizes, int n_in,
                              void* d_out, int out_size, void* d_ws, size_t ws_size,
                              hipStream_t stream)
{
    const float* hidden = (const float*)d_in[0];  // (2,2048,2048) f32
    const float* image  = (const float*)d_in[1];  // (2,8,64,2048) f32
    const int*   media  = (const int*)d_in[2];    // (2,2048)
    const float* Wq = (const float*)d_in[3];
    const float* Wk = (const float*)d_in[4];
    const float* Wv = (const float*)d_in[5];
    const float* Wo = (const float*)d_in[6];
    const float* lag = (const float*)d_in[7];
    const float* lab = (const float*)d_in[8];
    const float* lfg = (const float*)d_in[9];
    const float* lfb = (const float*)d_in[10];
    const float* W1 = (const float*)d_in[11];     // (2048, 8192)
    const float* b1 = (const float*)d_in[12];
    const float* W2 = (const float*)d_in[13];     // (8192, 2048)
    const float* b2 = (const float*)d_in[14];
    const float* ga = (const float*)d_in[15];
    const float* gf = (const float*)d_in[16];
    float* out = (float*)d_out;

    char* ws = (char*)d_ws;
    const size_t MB = 1ull << 20;
    bf16* WqT  = (bf16*)(ws + 0);
    bf16* WkT  = (bf16*)(ws + 8 * MB);
    bf16* WvT  = (bf16*)(ws + 16 * MB);
    bf16* WoT  = (bf16*)(ws + 24 * MB);
    bf16* W1T  = (bf16*)(ws + 0);         // reuses Wq..Wo region after attn
    bf16* W2T  = (bf16*)(ws + 32 * MB);   // reuses xln+q region after h1
    bf16* xln  = (bf16*)(ws + 32 * MB);
    bf16* q    = (bf16*)(ws + 48 * MB);
    bf16* kbuf = (bf16*)(ws + 64 * MB);
    bf16* vbuf = (bf16*)(ws + 68 * MB);
    bf16* vt   = (bf16*)(ws + 72 * MB);
    bf16* imgb = (bf16*)(ws + 76 * MB);
    bf16* sc   = (bf16*)(ws + 80 * MB);
    bf16* pa0  = (bf16*)(ws + 80 * MB);   // q/Wo split-K partials (16MB each)
    bf16* pa1  = (bf16*)(ws + 96 * MB);
    bf16* pw0  = (bf16*)(ws + 0);         // W2 split-K partials (W1T dead)
    bf16* pw1  = (bf16*)(ws + 16 * MB);
    float* x2  = (float*)(ws + 144 * MB);

    const float SCALE = 0.08838834764831845f; // 128^-0.5
    const long PSTRIDE = 4096L * 2048;        // partial-buffer stride (elems)
    dim3 blk(256);

    // f32 -> bf16 conversions / transposes (64m x 32n tiles)
    transpose_cvt<<<dim3(64, 32, 1), blk, 0, stream>>>(Wq, WqT, 2048, 2048);
    transpose_cvt<<<dim3(64, 32, 1), blk, 0, stream>>>(Wk, WkT, 2048, 2048);
    transpose_cvt<<<dim3(64, 32, 1), blk, 0, stream>>>(Wv, WvT, 2048, 2048);
    transpose_cvt<<<dim3(64, 32, 1), blk, 0, stream>>>(Wo, WoT, 2048, 2048);
    cvt_k<<<2048, blk, 0, stream>>>(image, imgb);   // 2*512*2048 elems

    // x = LN(hidden)  (f32 in, bf16 out)
    ln_k<<<4096, blk, 0, stream>>>(hidden, lag, lab, xln);

    // q = x @ Wq  (M=4096,N=2048,K=2048), split-K x2 -> grid 1024 = 4/CU
    gemm_bt<0, bf16><<<dim3(16, 32, 2), blk, 0, stream>>>(
        xln, WqT, pa0, 1024, 2048, 2048, 2048,
        0, 1024, 0, 1024, 0, PSTRIDE, 2, 1.f);
    reduce_q<<<4096, blk, 0, stream>>>(pa0, pa1, q);

    // k, v = image @ {Wk, Wv}  (M=1024, N=2048, K=2048; zi=0 -> k, zi=1 -> v)
    gemm_bt<0, bf16><<<dim3(16, 8, 2), blk, 0, stream>>>(
        imgb, WkT, kbuf, 2048, 2048, 2048, 2048,
        0, 0, 0, 4194304, 0, 2097152, 2, 1.f);

    // vt[b][h][d][kv] = v[b][kv][h*128+d]
    transpose_k<<<dim3(4, 16, 32), blk, 0, stream>>>(
        vbuf, vt, 2048, 512, 1048576, 128, 1048576, 65536, 16);

    // scores[b][h][s][kv] = SCALE * q_bh @ k_bh^T  (M=2048, N=512, K=128)
    gemm_bt<0, bf16><<<dim3(4, 16, 32), blk, 0, stream>>>(
        q, kbuf, sc, 128, 2048, 2048, 512,
        4194304, 128, 1048576, 128, 16777216, 1048576, 16, SCALE);

    // softmax over kv (in place)
    softmax512<<<16384, blk, 0, stream>>>(sc);

    // attn_out[b][s][h*128+d] = P_bh @ vt_bh^T  (M=2048, N=128, K=512)
    gemm_bt<0, bf16><<<dim3(1, 16, 32), blk, 0, stream>>>(
        sc, vt, q, 512, 512, 512, 2048,
        16777216, 1048576, 1048576, 65536, 4194304, 128, 16, 1.f);

    // attn_out @ Wo, split-K x2 (P in sc is dead after PV)
    gemm_bt<0, bf16><<<dim3(16, 32, 2), blk, 0, stream>>>(
        q, WoT, pa0, 1024, 2048, 2048, 2048,
        0, 1024, 0, 1024, 0, PSTRIDE, 2, 1.f);
    // x2 = hidden + tanh(ga) * (p0+p1) * mask
    reduce_wo<<<4096, blk, 0, stream>>>(pa0, pa1, hidden, ga, media, x2);

    // FFN weights (reuse dead regions)
    transpose_cvt<<<dim3(256, 32, 1), blk, 0, stream>>>(W1, W1T, 8192, 2048);

    // ln2 = LN(x2)
    ln_k<<<4096, blk, 0, stream>>>(x2, lfg, lfb, xln);

    // h1 = gelu(ln2 @ W1 + b1)  (M=4096, N=8192, K=2048) — 256^2 3-ring
    gemm256_h1<<<dim3(32, 16, 1), dim3(512), 0, stream>>>(
        xln, W1T, sc, 2048, 2048, 2048, 8192, b1);

    // W2T after h1 (xln, q dead now)
    transpose_cvt<<<dim3(64, 128, 1), blk, 0, stream>>>(W2, W2T, 2048, 8192);

    // h1 @ W2  (M=4096,N=2048,K=8192), split-K x2 -> grid 1024 = 4/CU
    gemm_bt<0, bf16><<<dim3(16, 32, 2), blk, 0, stream>>>(
        sc, W2T, pw0, 4096, 8192, 8192, 2048,
        0, 4096, 0, 4096, 0, PSTRIDE, 2, 1.f);
    // out = x2 + tanh(gf) * (p0+p1+b2)
    reduce_w2<<<4096, blk, 0, stream>>>(pw0, pw1, x2, b2, gf, out);
}

// Round 7
// 1083.862 us; speedup vs baseline: 1.0211x; 1.0211x over previous
//
#include <hip/hip_runtime.h>
#include <math.h>
#include <stdint.h>

typedef __bf16 bf16;
typedef __bf16 bf16x8 __attribute__((ext_vector_type(8)));
typedef __bf16 bf16x4 __attribute__((ext_vector_type(4)));
typedef float f32x4 __attribute__((ext_vector_type(4)));

#define DEV __device__ __forceinline__

// async global->LDS, 16B per lane. LDS dest must be wave-uniform base + lane*16.
DEV void g2l16(void* lds, const void* g) {
    __builtin_amdgcn_global_load_lds(
        (const __attribute__((address_space(1))) uint32_t*)g,
        (__attribute__((address_space(3))) uint32_t*)lds,
        16, 0, 0);
}

// Fast gelu: x * sigmoid(1.5957691216*(x + 0.044715 x^3)).
DEV float gelu_fast(float x) {
    float u = -1.5957691216f * __builtin_fmaf(0.044715f * x, x * x, x);
    return x * __builtin_amdgcn_rcpf(1.f + __expf(u));
}

// XCD-chunked block swizzle (T1): each XCD gets a contiguous chunk of tiles.
// Bijective iff nwg % 8 == 0 (guarded). Measured r5: W2 FETCH -33%, -8% dur.
DEV void xcd_swizzle(int& bx, int& by, int& bz) {
    int gx = gridDim.x, gy = gridDim.y, gz = gridDim.z;
    int nwg = gx * gy * gz;
    if (nwg & 7) return;
    long flat = ((long)bz * gy + by) * gx + bx;
    long q = nwg >> 3;
    long sw = (flat & 7) * q + (flat >> 3);
    bx = (int)(sw % gx);
    long t = sw / gx;
    by = (int)(t % gy);
    bz = (int)(t / gy);
}

// ---------------------------------------------------------------------------
// gemm3r: 256M x 128N tile, BK=64, 3-deep LDS ring, counted vmcnt.
// C = alpha * A @ Bt^T (+ epilogue). 512 threads = 8 waves (4M x 2N), each
// wave 64x64; per K-tile per wave = 32 MFMA between barriers (the invariant
// shared with gemm256_h1's measured ~680 TF; r3/r4's 16-MFMA variants failed).
// LDS 3 x (A 32KB + B 16KB) = 144KB -> 1 block/CU; grid (16,16)=256 fills the
// chip exactly without split-K (r6 lesson: split-K thrashes L2, no occ gain).
// Staging 6 g2l16/thread/tile; vmcnt(12) keeps tiles t+1,t+2 in flight across
// barriers (never drains). Tail stages 2 garbage tiles (<=256B past operand
// rows; all land in adjacent allocated ws regions; never consumed).
// EPI: 0 plain*alpha; 2 resid+tanh(g)*v*mask; 3 resid+tanh(g)*(v+bias)
// ---------------------------------------------------------------------------
template <int EPI, typename TC>
__global__ __launch_bounds__(512, 1)
void gemm3r(const bf16* __restrict__ A, const bf16* __restrict__ Bt, TC* __restrict__ C,
            int K, int lda, int ldb, int ldc, float alpha,
            const float* __restrict__ resid,
            const float* __restrict__ bias,
            const float* __restrict__ gamma,
            const int* __restrict__ mask)
{
    __shared__ bf16 ldsA[3][16384];  // [buf][kc 0..7][row 0..255][8]
    __shared__ bf16 ldsB[3][8192];   // [buf][kc 0..7][row 0..127][8]

    int bx = blockIdx.x, by = blockIdx.y, bz = blockIdx.z;
    xcd_swizzle(bx, by, bz);

    int tid = threadIdx.x;
    int wave = tid >> 6, lane = tid & 63, quad = lane >> 4, l15 = lane & 15;
    int wm = (wave >> 1) * 64, wn = (wave & 1) * 64;
    int tileN = bx * 128, tileM = by * 256;

    // staging: A c = r*512+tid (r=0..3), kc=c>>8, row=c&255;
    //          B c = r*512+tid (r=0..1), kc=c>>7, row=c&127
    const int cA0 = tid, cA1 = 512 + tid, cA2 = 1024 + tid, cA3 = 1536 + tid;
    const int cB0 = tid, cB1 = 512 + tid;
    const bf16* pA0 = A + (long)(tileM + (cA0 & 255)) * lda + (cA0 >> 8) * 8;
    const bf16* pA1 = A + (long)(tileM + (cA1 & 255)) * lda + (cA1 >> 8) * 8;
    const bf16* pA2 = A + (long)(tileM + (cA2 & 255)) * lda + (cA2 >> 8) * 8;
    const bf16* pA3 = A + (long)(tileM + (cA3 & 255)) * lda + (cA3 >> 8) * 8;
    const bf16* pB0 = Bt + (long)(tileN + (cB0 & 127)) * ldb + (cB0 >> 7) * 8;
    const bf16* pB1 = Bt + (long)(tileN + (cB1 & 127)) * ldb + (cB1 >> 7) * 8;

    f32x4 acc[4][4] = {};

    auto stage = [&](long t, int b) {
        long k0 = t << 6;
        g2l16(&ldsA[b][cA0 * 8], pA0 + k0);
        g2l16(&ldsA[b][cA1 * 8], pA1 + k0);
        g2l16(&ldsA[b][cA2 * 8], pA2 + k0);
        g2l16(&ldsA[b][cA3 * 8], pA3 + k0);
        g2l16(&ldsB[b][cB0 * 8], pB0 + k0);
        g2l16(&ldsB[b][cB1 * 8], pB1 + k0);
    };

    stage(0, 0);
    stage(1, 1);

    int T = K >> 6, cb = 0;
    for (int t = 0; t < T; ++t) {
        int nb = cb + 2; if (nb >= 3) nb -= 3;
        stage(t + 2, nb);   // garbage for t >= T-2; never consumed

        // wait tile t's 6 loads (18 outstanding -> 12); t+1,t+2 stay in flight
        asm volatile("s_waitcnt vmcnt(12)\n\ts_barrier" ::: "memory");

        const bf16* pa = ldsA[cb];
        const bf16* pb = ldsB[cb];
        bf16x8 af[2][4], bq[2][4];
#pragma unroll
        for (int ks = 0; ks < 2; ++ks)
#pragma unroll
            for (int i = 0; i < 4; ++i) {
                af[ks][i] = *(const bf16x8*)&pa[((ks * 4 + quad) * 256 + wm + i * 16 + l15) * 8];
                bq[ks][i] = *(const bf16x8*)&pb[((ks * 4 + quad) * 128 + wn + i * 16 + l15) * 8];
            }

        __builtin_amdgcn_s_setprio(1);
#pragma unroll
        for (int ks = 0; ks < 2; ++ks)
#pragma unroll
            for (int mi = 0; mi < 4; ++mi)
#pragma unroll
                for (int ni = 0; ni < 4; ++ni)
                    acc[mi][ni] = __builtin_amdgcn_mfma_f32_16x16x32_bf16(
                        af[ks][mi], bq[ks][ni], acc[mi][ni], 0, 0, 0);
        __builtin_amdgcn_s_setprio(0);

        asm volatile("s_barrier" ::: "memory");
        cb = (cb == 2) ? 0 : cb + 1;
    }

    float gscale = 0.f;
    if (EPI == 2 || EPI == 3) gscale = tanhf(gamma[0]);
    float bb[4] = {};
    if (EPI == 3) {
#pragma unroll
        for (int ni = 0; ni < 4; ++ni)
            bb[ni] = bias[tileN + wn + ni * 16 + l15];
    }

#pragma unroll
    for (int mi = 0; mi < 4; ++mi) {
#pragma unroll
        for (int r = 0; r < 4; ++r) {
            int gm = tileM + wm + mi * 16 + quad * 4 + r;
            float rowmask = 1.f;
            if (EPI == 2) rowmask = mask[gm] ? 1.f : 0.f;
#pragma unroll
            for (int ni = 0; ni < 4; ++ni) {
                int gn = tileN + wn + ni * 16 + l15;
                float v = acc[mi][ni][r] * alpha;
                float r0;
                if (EPI == 0) {
                    r0 = v;
                } else if (EPI == 2) {
                    float h = resid[(long)gm * ldc + gn];
                    r0 = h + gscale * v * rowmask;
                } else {
                    float h = resid[(long)gm * ldc + gn];
                    r0 = h + gscale * (v + bb[ni]);
                }
                C[(long)gm * ldc + gn] = (TC)r0;
            }
        }
    }
}

// ---------------------------------------------------------------------------
// Generic bf16 GEMM: C = alpha * A @ Bt^T. 128x128 tile, BK=64, 4 waves.
// Used for batched attention ops + k/v projection.
// ---------------------------------------------------------------------------
template <int EPI, typename TC>
__global__ __launch_bounds__(256)
void gemm_bt(const bf16* __restrict__ A, const bf16* __restrict__ Bt, TC* __restrict__ C,
             int K, int lda, int ldb, int ldc,
             long sAo, long sAi, long sBo, long sBi, long sCo, long sCi, int zInner,
             float alpha)
{
    int bx = blockIdx.x, by = blockIdx.y, bz = blockIdx.z;
    xcd_swizzle(bx, by, bz);

    int zo = bz / zInner, zi = bz % zInner;
    A  += (long)zo * sAo + (long)zi * sAi;
    Bt += (long)zo * sBo + (long)zi * sBi;
    long cOff = (long)zo * sCo + (long)zi * sCi;

    int tileN = bx * 128, tileM = by * 128;

    __shared__ bf16 As[8192];  // [kc][row][8]
    __shared__ bf16 Bs[8192];

    int tid = threadIdx.x;
    int wave = tid >> 6, lane = tid & 63, quad = lane >> 4, l15 = lane & 15;
    int wm = (wave >> 1) * 64, wn = (wave & 1) * 64;

    f32x4 acc[4][4] = {};

    for (int k0 = 0; k0 < K; k0 += 64) {
#pragma unroll
        for (int r = 0; r < 4; ++r) {
            int c = r * 256 + tid;
            int kc = c >> 7, row = c & 127;
            g2l16(&As[c * 8], A + (long)(tileM + row) * lda + (k0 + kc * 8));
            g2l16(&Bs[c * 8], Bt + (long)(tileN + row) * ldb + (k0 + kc * 8));
        }
        __syncthreads();
#pragma unroll
        for (int ks = 0; ks < 2; ++ks) {
            bf16x8 af[4], bq[4];
#pragma unroll
            for (int i = 0; i < 4; ++i) {
                af[i] = *(const bf16x8*)&As[((ks * 4 + quad) * 128 + wm + i * 16 + l15) * 8];
                bq[i] = *(const bf16x8*)&Bs[((ks * 4 + quad) * 128 + wn + i * 16 + l15) * 8];
            }
#pragma unroll
            for (int mi = 0; mi < 4; ++mi)
#pragma unroll
                for (int ni = 0; ni < 4; ++ni)
                    acc[mi][ni] = __builtin_amdgcn_mfma_f32_16x16x32_bf16(
                        af[mi], bq[ni], acc[mi][ni], 0, 0, 0);
        }
        __syncthreads();
    }

#pragma unroll
    for (int mi = 0; mi < 4; ++mi) {
#pragma unroll
        for (int r = 0; r < 4; ++r) {
            int gm = tileM + wm + mi * 16 + quad * 4 + r;
#pragma unroll
            for (int ni = 0; ni < 4; ++ni) {
                int gn = tileN + wn + ni * 16 + l15;
                C[cOff + (long)gm * ldc + gn] = (TC)(acc[mi][ni][r] * alpha);
            }
        }
    }
}

// ---------------------------------------------------------------------------
// Deep-pipelined 256x256 GEMM for h1: C = gelu(A @ Bt^T + bias), bf16 out.
// BK=32, 3-deep LDS ring (96KB), counted vmcnt(8). Measured ~680 TF.
// ---------------------------------------------------------------------------
__global__ __launch_bounds__(512, 2)
void gemm256_h1(const bf16* __restrict__ A, const bf16* __restrict__ Bt,
                bf16* __restrict__ C, int K, int lda, int ldb, int ldc,
                const float* __restrict__ bias)
{
    __shared__ bf16 lds[3][2][8192];   // [buf][A/B][kc*256+row][8] 16KB each

    int bx = blockIdx.x, by = blockIdx.y, bz = blockIdx.z;
    xcd_swizzle(bx, by, bz);

    int tid = threadIdx.x;
    int wave = tid >> 6, lane = tid & 63, quad = lane >> 4, l15 = lane & 15;
    int wm = (wave >> 2) * 128, wn = (wave & 3) * 64;
    int tileN = bx * 256, tileM = by * 256;

    int c0 = tid, c1 = 512 + tid;
    int kc0 = c0 >> 8, row0 = c0 & 255;
    int kc1 = c1 >> 8, row1 = c1 & 255;
    const bf16* A0 = A + (long)(tileM + row0) * lda + kc0 * 8;
    const bf16* A1 = A + (long)(tileM + row1) * lda + kc1 * 8;
    const bf16* B0 = Bt + (long)(tileN + row0) * ldb + kc0 * 8;
    const bf16* B1 = Bt + (long)(tileN + row1) * ldb + kc1 * 8;

    f32x4 acc[8][4] = {};

    int aoff = (quad * 256 + wm + l15) * 8;
    int boff = (quad * 256 + wn + l15) * 8;

    auto stage = [&](int t, int b) {
        int k0 = t * 32;
        g2l16(&lds[b][0][c0 * 8], A0 + k0);
        g2l16(&lds[b][0][c1 * 8], A1 + k0);
        g2l16(&lds[b][1][c0 * 8], B0 + k0);
        g2l16(&lds[b][1][c1 * 8], B1 + k0);
    };

    stage(0, 0);
    stage(1, 1);

    int T = K >> 5;
    int cb = 0;
    for (int t = 0; t < T; ++t) {
        int nb = cb + 2; if (nb >= 3) nb -= 3;
        stage(t + 2, nb);   // garbage for t >= T-2; never consumed (in-ws reads)

        asm volatile("s_waitcnt vmcnt(8)\n\ts_barrier" ::: "memory");

        const bf16* pA = &lds[cb][0][0];
        const bf16* pB = &lds[cb][1][0];
        bf16x8 af[8], bq[4];
#pragma unroll
        for (int mi = 0; mi < 8; ++mi)
            af[mi] = *(const bf16x8*)&pA[aoff + mi * 128];
#pragma unroll
        for (int ni = 0; ni < 4; ++ni)
            bq[ni] = *(const bf16x8*)&pB[boff + ni * 128];

        __builtin_amdgcn_s_setprio(1);
#pragma unroll
        for (int mi = 0; mi < 8; ++mi)
#pragma unroll
            for (int ni = 0; ni < 4; ++ni)
                acc[mi][ni] = __builtin_amdgcn_mfma_f32_16x16x32_bf16(
                    af[mi], bq[ni], acc[mi][ni], 0, 0, 0);
        __builtin_amdgcn_s_setprio(0);

        asm volatile("s_barrier" ::: "memory");
        cb = (cb == 2) ? 0 : cb + 1;
    }

    float bb[4];
#pragma unroll
    for (int ni = 0; ni < 4; ++ni)
        bb[ni] = bias[tileN + wn + ni * 16 + l15];

#pragma unroll
    for (int mi = 0; mi < 8; ++mi) {
#pragma unroll
        for (int r = 0; r < 4; ++r) {
            int gm = tileM + wm + mi * 16 + quad * 4 + r;
#pragma unroll
            for (int ni = 0; ni < 4; ++ni) {
                int gn = tileN + wn + ni * 16 + l15;
                float x = acc[mi][ni][r] + bb[ni];
                C[(long)gm * ldc + gn] = (bf16)gelu_fast(x);
            }
        }
    }
}

// ---------------------------------------------------------------------------
// LayerNorm over rows of 2048 (f32 in, f32 params, bf16 out). One row/block.
// ---------------------------------------------------------------------------
__global__ __launch_bounds__(256)
void ln_k(const float* __restrict__ x, const float* __restrict__ g, const float* __restrict__ b,
          bf16* __restrict__ out)
{
    long row = blockIdx.x;
    int tid = threadIdx.x;
    int wave = tid >> 6, lane = tid & 63;
    const float* px = x + row * 2048 + tid * 8;

    float4 a = *(const float4*)px;
    float4 c = *(const float4*)(px + 4);
    float f[8] = {a.x, a.y, a.z, a.w, c.x, c.y, c.z, c.w};

    float s = 0.f, s2 = 0.f;
#pragma unroll
    for (int j = 0; j < 8; ++j) { s += f[j]; s2 += f[j] * f[j]; }
    for (int o = 32; o; o >>= 1) { s += __shfl_xor(s, o, 64); s2 += __shfl_xor(s2, o, 64); }

    __shared__ float red[8];
    if (lane == 0) { red[wave] = s; red[4 + wave] = s2; }
    __syncthreads();
    s  = red[0] + red[1] + red[2] + red[3];
    s2 = red[4] + red[5] + red[6] + red[7];

    float mean = s * (1.f / 2048.f);
    float var  = s2 * (1.f / 2048.f) - mean * mean;
    float rstd = rsqrtf(var + 1e-5f);

    int col = tid * 8;
    bf16x8 o8;
#pragma unroll
    for (int j = 0; j < 8; ++j)
        o8[j] = (bf16)((f[j] - mean) * rstd * g[col + j] + b[col + j]);
    *(bf16x8*)(out + row * 2048 + tid * 8) = o8;
}

// ---------------------------------------------------------------------------
// Row softmax over 512 (in-place, bf16). One wave per row, 4 rows per block.
// ---------------------------------------------------------------------------
__global__ __launch_bounds__(256)
void softmax512(bf16* __restrict__ s)
{
    long row = (long)blockIdx.x * 4 + (threadIdx.x >> 6);
    int lane = threadIdx.x & 63;
    bf16* p = s + row * 512 + lane * 8;
    bf16x8 v = *(const bf16x8*)p;
    float f[8], mx = -1e30f;
#pragma unroll
    for (int j = 0; j < 8; ++j) { f[j] = (float)v[j]; mx = fmaxf(mx, f[j]); }
    for (int o = 32; o; o >>= 1) mx = fmaxf(mx, __shfl_xor(mx, o, 64));
    float sum = 0.f;
#pragma unroll
    for (int j = 0; j < 8; ++j) { f[j] = __expf(f[j] - mx); sum += f[j]; }
    for (int o = 32; o; o >>= 1) sum += __shfl_xor(sum, o, 64);
    float r = 1.f / sum;
    bf16x8 o8;
#pragma unroll
    for (int j = 0; j < 8; ++j) o8[j] = (bf16)(f[j] * r);
    *(bf16x8*)p = o8;
}

// ---------------------------------------------------------------------------
// Transpose f32 -> bf16: out[n][m] = (bf16)in[m][n]. Tile 64m x 32n, 256 thr.
// bf16x4 writes -> 128B contiguous per 16 lanes.
// ---------------------------------------------------------------------------
__global__ __launch_bounds__(256)
void transpose_cvt(const float* __restrict__ in, bf16* __restrict__ out, int ldi, int ldo)
{
    __shared__ float t[64][33];
    int tx = threadIdx.x & 31, ty = threadIdx.x >> 5;
    int n0 = blockIdx.x * 32, m0 = blockIdx.y * 64;
#pragma unroll
    for (int i = 0; i < 8; ++i)
        t[ty + i * 8][tx] = in[(long)(m0 + ty + i * 8) * ldi + n0 + tx];
    __syncthreads();
    int wx = threadIdx.x & 15, wy = threadIdx.x >> 4;
#pragma unroll
    for (int j = 0; j < 2; ++j) {
        int n = wy + j * 16;
        bf16x4 v;
        v[0] = (bf16)t[4 * wx + 0][n];
        v[1] = (bf16)t[4 * wx + 1][n];
        v[2] = (bf16)t[4 * wx + 2][n];
        v[3] = (bf16)t[4 * wx + 3][n];
        *(bf16x4*)(out + (long)(n0 + n) * ldo + m0 + 4 * wx) = v;
    }
}

// ---------------------------------------------------------------------------
// Batched bf16 transpose (for V): out[n][m] = in[m][n]. Tile 32x32.
// ---------------------------------------------------------------------------
__global__ __launch_bounds__(256)
void transpose_k(const bf16* __restrict__ in, bf16* __restrict__ out,
                 int ldi, int ldo, long sIo, long sIi, long sOo, long sOi, int zInner)
{
    int z = blockIdx.z;
    in  += (long)(z / zInner) * sIo + (long)(z % zInner) * sIi;
    out += (long)(z / zInner) * sOo + (long)(z % zInner) * sOi;
    __shared__ bf16 t[32][33];
    int tx = threadIdx.x & 31, ty = threadIdx.x >> 5;
    int n0 = blockIdx.x * 32, m0 = blockIdx.y * 32;
#pragma unroll
    for (int i = 0; i < 4; ++i)
        t[ty + i * 8][tx] = in[(long)(m0 + ty + i * 8) * ldi + n0 + tx];
    __syncthreads();
#pragma unroll
    for (int i = 0; i < 4; ++i)
        out[(long)(n0 + ty + i * 8) * ldo + m0 + tx] = t[tx][ty + i * 8];
}

// f32 -> bf16 elementwise (for image_embeds). 4 elems/thread.
__global__ __launch_bounds__(256)
void cvt_k(const float* __restrict__ in, bf16* __restrict__ out)
{
    int i = (blockIdx.x * 256 + threadIdx.x) * 4;
    float4 v = *(const float4*)(in + i);
    out[i + 0] = (bf16)v.x;
    out[i + 1] = (bf16)v.y;
    out[i + 2] = (bf16)v.z;
    out[i + 3] = (bf16)v.w;
}

// ---------------------------------------------------------------------------
// Workspace layout (MiB offsets), peak 176 MiB:
//   0-32   : WqT(0) WkT(8) WvT(16) WoT(24)  -> later W1T(0-32)
//   32-48  : xln        -> later W2T low half
//   48-64  : q/attn_out -> later W2T high half
//   64-68  : kbuf   68-72: vbuf   72-76: vt   76-80: imgb
//   80-144 : sc (scores -> P -> h1)
//   144-176: x2 (f32)
// gemm3r tail reads (<=2 BK-tiles past K per row): q: xln->q, WqT->WkT;
// Wo: q->kbuf, WoT->xln; W2: sc->x2, W2T->kbuf. All in allocated ws.
// ---------------------------------------------------------------------------
extern "C" void kernel_launch(void* const* d_in, const int* in_sizes, int n_in,
                              void* d_out, int out_size, void* d_ws, size_t ws_size,
                              hipStream_t stream)
{
    const float* hidden = (const float*)d_in[0];  // (2,2048,2048) f32
    const float* image  = (const float*)d_in[1];  // (2,8,64,2048) f32
    const int*   media  = (const int*)d_in[2];    // (2,2048)
    const float* Wq = (const float*)d_in[3];
    const float* Wk = (const float*)d_in[4];
    const float* Wv = (const float*)d_in[5];
    const float* Wo = (const float*)d_in[6];
    const float* lag = (const float*)d_in[7];
    const float* lab = (const float*)d_in[8];
    const float* lfg = (const float*)d_in[9];
    const float* lfb = (const float*)d_in[10];
    const float* W1 = (const float*)d_in[11];     // (2048, 8192)
    const float* b1 = (const float*)d_in[12];
    const float* W2 = (const float*)d_in[13];     // (8192, 2048)
    const float* b2 = (const float*)d_in[14];
    const float* ga = (const float*)d_in[15];
    const float* gf = (const float*)d_in[16];
    float* out = (float*)d_out;

    char* ws = (char*)d_ws;
    const size_t MB = 1ull << 20;
    bf16* WqT  = (bf16*)(ws + 0);
    bf16* WkT  = (bf16*)(ws + 8 * MB);
    bf16* WvT  = (bf16*)(ws + 16 * MB);
    bf16* WoT  = (bf16*)(ws + 24 * MB);
    bf16* W1T  = (bf16*)(ws + 0);         // reuses Wq..Wo region after attn
    bf16* W2T  = (bf16*)(ws + 32 * MB);   // reuses xln+q region after h1
    bf16* xln  = (bf16*)(ws + 32 * MB);
    bf16* q    = (bf16*)(ws + 48 * MB);
    bf16* kbuf = (bf16*)(ws + 64 * MB);
    bf16* vbuf = (bf16*)(ws + 68 * MB);
    bf16* vt   = (bf16*)(ws + 72 * MB);
    bf16* imgb = (bf16*)(ws + 76 * MB);
    bf16* sc   = (bf16*)(ws + 80 * MB);
    float* x2  = (float*)(ws + 144 * MB);

    const float SCALE = 0.08838834764831845f; // 128^-0.5
    dim3 blk(256);

    // f32 -> bf16 conversions / transposes
    transpose_cvt<<<dim3(64, 32, 1), blk, 0, stream>>>(Wq, WqT, 2048, 2048);
    transpose_cvt<<<dim3(64, 32, 1), blk, 0, stream>>>(Wk, WkT, 2048, 2048);
    transpose_cvt<<<dim3(64, 32, 1), blk, 0, stream>>>(Wv, WvT, 2048, 2048);
    transpose_cvt<<<dim3(64, 32, 1), blk, 0, stream>>>(Wo, WoT, 2048, 2048);
    cvt_k<<<2048, blk, 0, stream>>>(image, imgb);   // 2*512*2048 elems

    // x = LN(hidden)  (f32 in, bf16 out)
    ln_k<<<4096, blk, 0, stream>>>(hidden, lag, lab, xln);

    // q = x @ Wq   (M=4096, N=2048, K=2048) — 256x128 3-ring, grid 256 = 1/CU
    gemm3r<0, bf16><<<dim3(16, 16, 1), dim3(512), 0, stream>>>(
        xln, WqT, q, 2048, 2048, 2048, 2048, 1.f,
        nullptr, nullptr, nullptr, nullptr);

    // k, v = image @ {Wk, Wv}  (M=1024, N=2048, K=2048; zi=0 -> k, zi=1 -> v)
    gemm_bt<0, bf16><<<dim3(16, 8, 2), blk, 0, stream>>>(
        imgb, WkT, kbuf, 2048, 2048, 2048, 2048,
        0, 0, 0, 4194304, 0, 2097152, 2, 1.f);

    // vt[b][h][d][kv] = v[b][kv][h*128+d]
    transpose_k<<<dim3(4, 16, 32), blk, 0, stream>>>(
        vbuf, vt, 2048, 512, 1048576, 128, 1048576, 65536, 16);

    // scores[b][h][s][kv] = SCALE * q_bh @ k_bh^T  (M=2048, N=512, K=128)
    gemm_bt<0, bf16><<<dim3(4, 16, 32), blk, 0, stream>>>(
        q, kbuf, sc, 128, 2048, 2048, 512,
        4194304, 128, 1048576, 128, 16777216, 1048576, 16, SCALE);

    // softmax over kv (in place)
    softmax512<<<16384, blk, 0, stream>>>(sc);

    // attn_out[b][s][h*128+d] = P_bh @ vt_bh^T  (M=2048, N=128, K=512)
    gemm_bt<0, bf16><<<dim3(1, 16, 32), blk, 0, stream>>>(
        sc, vt, q, 512, 512, 512, 2048,
        16777216, 1048576, 1048576, 65536, 4194304, 128, 16, 1.f);

    // x2 = hidden + tanh(ga) * (attn_out @ Wo) * mask   (f32 out)
    gemm3r<2, float><<<dim3(16, 16, 1), dim3(512), 0, stream>>>(
        q, WoT, x2, 2048, 2048, 2048, 2048, 1.f,
        hidden, nullptr, ga, media);

    // FFN weights (reuse dead regions)
    transpose_cvt<<<dim3(256, 32, 1), blk, 0, stream>>>(W1, W1T, 8192, 2048);

    // ln2 = LN(x2)
    ln_k<<<4096, blk, 0, stream>>>(x2, lfg, lfb, xln);

    // h1 = gelu(ln2 @ W1 + b1)  (M=4096, N=8192, K=2048) — 256^2 3-ring
    gemm256_h1<<<dim3(32, 16, 1), dim3(512), 0, stream>>>(
        xln, W1T, sc, 2048, 2048, 2048, 8192, b1);

    // W2T after h1 (xln, q dead now)
    transpose_cvt<<<dim3(64, 128, 1), blk, 0, stream>>>(W2, W2T, 2048, 8192);

    // out = x2 + tanh(gf) * (h1 @ W2 + b2)  (M=4096, N=2048, K=8192, f32 out)
    gemm3r<3, float><<<dim3(16, 16, 1), dim3(512), 0, stream>>>(
        sc, W2T, out, 8192, 8192, 8192, 2048, 1.f,
        x2, b2, gf, nullptr);
}

// Round 8
// 916.463 us; speedup vs baseline: 1.2076x; 1.1827x over previous
//
#include <hip/hip_runtime.h>
#include <math.h>
#include <stdint.h>

typedef __bf16 bf16;
typedef __bf16 bf16x8 __attribute__((ext_vector_type(8)));
typedef __bf16 bf16x4 __attribute__((ext_vector_type(4)));
typedef float f32x4 __attribute__((ext_vector_type(4)));

#define DEV __device__ __forceinline__

// async global->LDS, 16B per lane. LDS dest must be wave-uniform base + lane*16.
DEV void g2l16(void* lds, const void* g) {
    __builtin_amdgcn_global_load_lds(
        (const __attribute__((address_space(1))) uint32_t*)g,
        (__attribute__((address_space(3))) uint32_t*)lds,
        16, 0, 0);
}

// Fast gelu: x * sigmoid(1.5957691216*(x + 0.044715 x^3)).
DEV float gelu_fast(float x) {
    float u = -1.5957691216f * __builtin_fmaf(0.044715f * x, x * x, x);
    return x * __builtin_amdgcn_rcpf(1.f + __expf(u));
}

// f32 -> OCP e4m3 byte (single value, saturating hardware convert).
DEV uint8_t to_fp8(float x) {
    return (uint8_t)(__builtin_amdgcn_cvt_pk_fp8_f32(x, x, 0, false) & 0xff);
}

// XCD-chunked block swizzle (T1): each XCD gets a contiguous chunk of tiles.
// Bijective iff nwg % 8 == 0 (guarded). Measured r5: W2 FETCH -33%, -8% dur.
DEV void xcd_swizzle(int& bx, int& by, int& bz) {
    int gx = gridDim.x, gy = gridDim.y, gz = gridDim.z;
    int nwg = gx * gy * gz;
    if (nwg & 7) return;
    long flat = ((long)bz * gy + by) * gx + bx;
    long q = nwg >> 3;
    long sw = (flat & 7) * q + (flat >> 3);
    bx = (int)(sw % gx);
    long t = sw / gx;
    by = (int)(t % gy);
    bz = (int)(t / gy);
}

// ---------------------------------------------------------------------------
// Generic bf16 GEMM: C = alpha * A @ Bt^T (+ epilogue). 128x128 tile, BK=64,
// 4 waves (2x2), wave 64x64 via 4x4 mfma_f32_16x16x32_bf16. Conflict-free
// k-chunked LDS. Staging-BW model: 64 FLOP/staged-byte x ~7.6 TB/s ≈ 497 TF
// (measured r5). EPI: 0 plain*alpha; 2 resid+tanh(g)*v*mask.
// ---------------------------------------------------------------------------
template <int EPI, typename TC>
__global__ __launch_bounds__(256)
void gemm_bt(const bf16* __restrict__ A, const bf16* __restrict__ Bt, TC* __restrict__ C,
             int K, int lda, int ldb, int ldc,
             long sAo, long sAi, long sBo, long sBi, long sCo, long sCi, int zInner,
             float alpha,
             const float* __restrict__ resid,
             const float* __restrict__ gamma,
             const int* __restrict__ mask)
{
    int bx = blockIdx.x, by = blockIdx.y, bz = blockIdx.z;
    xcd_swizzle(bx, by, bz);

    int zo = bz / zInner, zi = bz % zInner;
    A  += (long)zo * sAo + (long)zi * sAi;
    Bt += (long)zo * sBo + (long)zi * sBi;
    long cOff = (long)zo * sCo + (long)zi * sCi;

    int tileN = bx * 128, tileM = by * 128;

    __shared__ bf16 As[8192];  // [kc][row][8]
    __shared__ bf16 Bs[8192];

    int tid = threadIdx.x;
    int wave = tid >> 6, lane = tid & 63, quad = lane >> 4, l15 = lane & 15;
    int wm = (wave >> 1) * 64, wn = (wave & 1) * 64;

    f32x4 acc[4][4] = {};

    for (int k0 = 0; k0 < K; k0 += 64) {
#pragma unroll
        for (int r = 0; r < 4; ++r) {
            int c = r * 256 + tid;
            int kc = c >> 7, row = c & 127;
            g2l16(&As[c * 8], A + (long)(tileM + row) * lda + (k0 + kc * 8));
            g2l16(&Bs[c * 8], Bt + (long)(tileN + row) * ldb + (k0 + kc * 8));
        }
        __syncthreads();
#pragma unroll
        for (int ks = 0; ks < 2; ++ks) {
            bf16x8 af[4], bq[4];
#pragma unroll
            for (int i = 0; i < 4; ++i) {
                af[i] = *(const bf16x8*)&As[((ks * 4 + quad) * 128 + wm + i * 16 + l15) * 8];
                bq[i] = *(const bf16x8*)&Bs[((ks * 4 + quad) * 128 + wn + i * 16 + l15) * 8];
            }
#pragma unroll
            for (int mi = 0; mi < 4; ++mi)
#pragma unroll
                for (int ni = 0; ni < 4; ++ni)
                    acc[mi][ni] = __builtin_amdgcn_mfma_f32_16x16x32_bf16(
                        af[mi], bq[ni], acc[mi][ni], 0, 0, 0);
        }
        __syncthreads();
    }

    float gscale = 0.f;
    if (EPI == 2) gscale = tanhf(gamma[0]);

#pragma unroll
    for (int mi = 0; mi < 4; ++mi) {
#pragma unroll
        for (int r = 0; r < 4; ++r) {
            int gm = tileM + wm + mi * 16 + quad * 4 + r;
            float rowmask = 1.f;
            if (EPI == 2) rowmask = mask[gm] ? 1.f : 0.f;
#pragma unroll
            for (int ni = 0; ni < 4; ++ni) {
                int gn = tileN + wn + ni * 16 + l15;
                float v = acc[mi][ni][r] * alpha;
                float r0;
                if (EPI == 0) {
                    r0 = v;
                } else {
                    float h = resid[(long)gm * ldc + gn];
                    r0 = h + gscale * v * rowmask;
                }
                C[cOff + (long)gm * ldc + gn] = (TC)r0;
            }
        }
    }
}

// ---------------------------------------------------------------------------
// fp8 (e4m3) GEMM for W2: out = resid + tanh(gamma)*(alpha*A@Bt^T + bias).
// A: M x K fp8 row-major; Bt: N x K fp8 row-major. Tile 128x128, BK=128:
// staged bytes per K-tile identical to the bf16 kernel (32KB) but 2x FLOP ->
// intensity 128 FLOP/staged-byte. Under the staging-BW model (7.6 TB/s at
// 2 blocks/CU) predicts ~970 TF vs bf16's 497. Fragment mapping mirrors the
// verified bf16 16x16x32 layout: lane's 8 k-elems = (32-step ks, k_rel =
// quad*8..+7), i.e. LDS [kc16][row][16B] chunk kc16 = ks*2 + (quad>>1),
// byte offset (quad&1)*8, read as i64 for mfma_f32_16x16x32_fp8_fp8.
// ---------------------------------------------------------------------------
__global__ __launch_bounds__(256)
void gemm_fp8(const uint8_t* __restrict__ A, const uint8_t* __restrict__ Bt,
              float* __restrict__ C, int K, int lda, int ldb, int ldc, float alpha,
              const float* __restrict__ resid,
              const float* __restrict__ bias,
              const float* __restrict__ gamma)
{
    int bx = blockIdx.x, by = blockIdx.y, bz = blockIdx.z;
    xcd_swizzle(bx, by, bz);

    int tileN = bx * 128, tileM = by * 128;

    __shared__ uint8_t As[16384];  // [kc16 0..7][row 0..127][16]
    __shared__ uint8_t Bs[16384];

    int tid = threadIdx.x;
    int wave = tid >> 6, lane = tid & 63, quad = lane >> 4, l15 = lane & 15;
    int wm = (wave >> 1) * 64, wn = (wave & 1) * 64;

    f32x4 acc[4][4] = {};

    for (int k0 = 0; k0 < K; k0 += 128) {
#pragma unroll
        for (int r = 0; r < 4; ++r) {
            int c = r * 256 + tid;              // c = kc16*128 + row
            int kc = c >> 7, row = c & 127;
            g2l16(&As[c * 16], A + (long)(tileM + row) * lda + (k0 + kc * 16));
            g2l16(&Bs[c * 16], Bt + (long)(tileN + row) * ldb + (k0 + kc * 16));
        }
        __syncthreads();
#pragma unroll
        for (int ks = 0; ks < 4; ++ks) {        // 4 x 32-k MFMA steps
            int kc16 = ks * 2 + (quad >> 1);
            int boff = (quad & 1) * 8;
            long af[4], bq[4];
#pragma unroll
            for (int i = 0; i < 4; ++i) {
                af[i] = *(const long*)&As[(kc16 * 128 + wm + i * 16 + l15) * 16 + boff];
                bq[i] = *(const long*)&Bs[(kc16 * 128 + wn + i * 16 + l15) * 16 + boff];
            }
#pragma unroll
            for (int mi = 0; mi < 4; ++mi)
#pragma unroll
                for (int ni = 0; ni < 4; ++ni)
                    acc[mi][ni] = __builtin_amdgcn_mfma_f32_16x16x32_fp8_fp8(
                        af[mi], bq[ni], acc[mi][ni], 0, 0, 0);
        }
        __syncthreads();
    }

    float gscale = tanhf(gamma[0]);
    float bb[4];
#pragma unroll
    for (int ni = 0; ni < 4; ++ni)
        bb[ni] = bias[tileN + wn + ni * 16 + l15];

#pragma unroll
    for (int mi = 0; mi < 4; ++mi) {
#pragma unroll
        for (int r = 0; r < 4; ++r) {
            int gm = tileM + wm + mi * 16 + quad * 4 + r;
#pragma unroll
            for (int ni = 0; ni < 4; ++ni) {
                int gn = tileN + wn + ni * 16 + l15;
                float h = resid[(long)gm * ldc + gn];
                C[(long)gm * ldc + gn] = h + gscale * (acc[mi][ni][r] * alpha + bb[ni]);
            }
        }
    }
}

// ---------------------------------------------------------------------------
// Deep-pipelined 256x256 GEMM for h1: C8 = fp8(8 * gelu(A @ Bt^T + bias)).
// BK=32, 3-deep LDS ring (96KB), counted vmcnt(8). Measured ~680 TF.
// Output is e4m3 (scale 8: gelu range (-0.17, ~6) -> (-1.4, 48), well inside
// e4m3 normal range; consumed by gemm_fp8 with alpha = 1/(8*64)).
// ---------------------------------------------------------------------------
__global__ __launch_bounds__(512, 2)
void gemm256_h1(const bf16* __restrict__ A, const bf16* __restrict__ Bt,
                uint8_t* __restrict__ C, int K, int lda, int ldb, int ldc,
                const float* __restrict__ bias)
{
    __shared__ bf16 lds[3][2][8192];   // [buf][A/B][kc*256+row][8] 16KB each

    int bx = blockIdx.x, by = blockIdx.y, bz = blockIdx.z;
    xcd_swizzle(bx, by, bz);

    int tid = threadIdx.x;
    int wave = tid >> 6, lane = tid & 63, quad = lane >> 4, l15 = lane & 15;
    int wm = (wave >> 2) * 128, wn = (wave & 3) * 64;
    int tileN = bx * 256, tileM = by * 256;

    int c0 = tid, c1 = 512 + tid;
    int kc0 = c0 >> 8, row0 = c0 & 255;
    int kc1 = c1 >> 8, row1 = c1 & 255;
    const bf16* A0 = A + (long)(tileM + row0) * lda + kc0 * 8;
    const bf16* A1 = A + (long)(tileM + row1) * lda + kc1 * 8;
    const bf16* B0 = Bt + (long)(tileN + row0) * ldb + kc0 * 8;
    const bf16* B1 = Bt + (long)(tileN + row1) * ldb + kc1 * 8;

    f32x4 acc[8][4] = {};

    int aoff = (quad * 256 + wm + l15) * 8;
    int boff = (quad * 256 + wn + l15) * 8;

    auto stage = [&](int t, int b) {
        int k0 = t * 32;
        g2l16(&lds[b][0][c0 * 8], A0 + k0);
        g2l16(&lds[b][0][c1 * 8], A1 + k0);
        g2l16(&lds[b][1][c0 * 8], B0 + k0);
        g2l16(&lds[b][1][c1 * 8], B1 + k0);
    };

    stage(0, 0);
    stage(1, 1);

    int T = K >> 5;
    int cb = 0;
    for (int t = 0; t < T; ++t) {
        int nb = cb + 2; if (nb >= 3) nb -= 3;
        stage(t + 2, nb);   // garbage for t >= T-2; never consumed (in-ws reads)

        asm volatile("s_waitcnt vmcnt(8)\n\ts_barrier" ::: "memory");

        const bf16* pA = &lds[cb][0][0];
        const bf16* pB = &lds[cb][1][0];
        bf16x8 af[8], bq[4];
#pragma unroll
        for (int mi = 0; mi < 8; ++mi)
            af[mi] = *(const bf16x8*)&pA[aoff + mi * 128];
#pragma unroll
        for (int ni = 0; ni < 4; ++ni)
            bq[ni] = *(const bf16x8*)&pB[boff + ni * 128];

        __builtin_amdgcn_s_setprio(1);
#pragma unroll
        for (int mi = 0; mi < 8; ++mi)
#pragma unroll
            for (int ni = 0; ni < 4; ++ni)
                acc[mi][ni] = __builtin_amdgcn_mfma_f32_16x16x32_bf16(
                    af[mi], bq[ni], acc[mi][ni], 0, 0, 0);
        __builtin_amdgcn_s_setprio(0);

        asm volatile("s_barrier" ::: "memory");
        cb = (cb == 2) ? 0 : cb + 1;
    }

    float bb[4];
#pragma unroll
    for (int ni = 0; ni < 4; ++ni)
        bb[ni] = bias[tileN + wn + ni * 16 + l15];

#pragma unroll
    for (int mi = 0; mi < 8; ++mi) {
#pragma unroll
        for (int r = 0; r < 4; ++r) {
            int gm = tileM + wm + mi * 16 + quad * 4 + r;
#pragma unroll
            for (int ni = 0; ni < 4; ++ni) {
                int gn = tileN + wn + ni * 16 + l15;
                float x = acc[mi][ni][r] + bb[ni];
                C[(long)gm * ldc + gn] = to_fp8(8.f * gelu_fast(x));
            }
        }
    }
}

// ---------------------------------------------------------------------------
// LayerNorm over rows of 2048 (f32 in, f32 params, bf16 out). One row/block.
// ---------------------------------------------------------------------------
__global__ __launch_bounds__(256)
void ln_k(const float* __restrict__ x, const float* __restrict__ g, const float* __restrict__ b,
          bf16* __restrict__ out)
{
    long row = blockIdx.x;
    int tid = threadIdx.x;
    int wave = tid >> 6, lane = tid & 63;
    const float* px = x + row * 2048 + tid * 8;

    float4 a = *(const float4*)px;
    float4 c = *(const float4*)(px + 4);
    float f[8] = {a.x, a.y, a.z, a.w, c.x, c.y, c.z, c.w};

    float s = 0.f, s2 = 0.f;
#pragma unroll
    for (int j = 0; j < 8; ++j) { s += f[j]; s2 += f[j] * f[j]; }
    for (int o = 32; o; o >>= 1) { s += __shfl_xor(s, o, 64); s2 += __shfl_xor(s2, o, 64); }

    __shared__ float red[8];
    if (lane == 0) { red[wave] = s; red[4 + wave] = s2; }
    __syncthreads();
    s  = red[0] + red[1] + red[2] + red[3];
    s2 = red[4] + red[5] + red[6] + red[7];

    float mean = s * (1.f / 2048.f);
    float var  = s2 * (1.f / 2048.f) - mean * mean;
    float rstd = rsqrtf(var + 1e-5f);

    int col = tid * 8;
    bf16x8 o8;
#pragma unroll
    for (int j = 0; j < 8; ++j)
        o8[j] = (bf16)((f[j] - mean) * rstd * g[col + j] + b[col + j]);
    *(bf16x8*)(out + row * 2048 + tid * 8) = o8;
}

// ---------------------------------------------------------------------------
// Row softmax over 512 (in-place, bf16). One wave per row, 4 rows per block.
// ---------------------------------------------------------------------------
__global__ __launch_bounds__(256)
void softmax512(bf16* __restrict__ s)
{
    long row = (long)blockIdx.x * 4 + (threadIdx.x >> 6);
    int lane = threadIdx.x & 63;
    bf16* p = s + row * 512 + lane * 8;
    bf16x8 v = *(const bf16x8*)p;
    float f[8], mx = -1e30f;
#pragma unroll
    for (int j = 0; j < 8; ++j) { f[j] = (float)v[j]; mx = fmaxf(mx, f[j]); }
    for (int o = 32; o; o >>= 1) mx = fmaxf(mx, __shfl_xor(mx, o, 64));
    float sum = 0.f;
#pragma unroll
    for (int j = 0; j < 8; ++j) { f[j] = __expf(f[j] - mx); sum += f[j]; }
    for (int o = 32; o; o >>= 1) sum += __shfl_xor(sum, o, 64);
    float r = 1.f / sum;
    bf16x8 o8;
#pragma unroll
    for (int j = 0; j < 8; ++j) o8[j] = (bf16)(f[j] * r);
    *(bf16x8*)p = o8;
}

// ---------------------------------------------------------------------------
// Transpose f32 -> bf16: out[n][m] = (bf16)in[m][n]. Tile 64m x 32n, 256 thr.
// ---------------------------------------------------------------------------
__global__ __launch_bounds__(256)
void transpose_cvt(const float* __restrict__ in, bf16* __restrict__ out, int ldi, int ldo)
{
    __shared__ float t[64][33];
    int tx = threadIdx.x & 31, ty = threadIdx.x >> 5;
    int n0 = blockIdx.x * 32, m0 = blockIdx.y * 64;
#pragma unroll
    for (int i = 0; i < 8; ++i)
        t[ty + i * 8][tx] = in[(long)(m0 + ty + i * 8) * ldi + n0 + tx];
    __syncthreads();
    int wx = threadIdx.x & 15, wy = threadIdx.x >> 4;
#pragma unroll
    for (int j = 0; j < 2; ++j) {
        int n = wy + j * 16;
        bf16x4 v;
        v[0] = (bf16)t[4 * wx + 0][n];
        v[1] = (bf16)t[4 * wx + 1][n];
        v[2] = (bf16)t[4 * wx + 2][n];
        v[3] = (bf16)t[4 * wx + 3][n];
        *(bf16x4*)(out + (long)(n0 + n) * ldo + m0 + 4 * wx) = v;
    }
}

// ---------------------------------------------------------------------------
// Transpose f32 -> fp8 e4m3 (x scale): out[n][m] = fp8(scale*in[m][n]).
// Tile 64m x 32n; 4-byte packed stores via v_cvt_pk_fp8_f32.
// ---------------------------------------------------------------------------
__global__ __launch_bounds__(256)
void transpose_cvt8(const float* __restrict__ in, uint8_t* __restrict__ out,
                    int ldi, int ldo, float scale)
{
    __shared__ float t[64][33];
    int tx = threadIdx.x & 31, ty = threadIdx.x >> 5;
    int n0 = blockIdx.x * 32, m0 = blockIdx.y * 64;
#pragma unroll
    for (int i = 0; i < 8; ++i)
        t[ty + i * 8][tx] = in[(long)(m0 + ty + i * 8) * ldi + n0 + tx];
    __syncthreads();
    int wx = threadIdx.x & 15, wy = threadIdx.x >> 4;
#pragma unroll
    for (int j = 0; j < 2; ++j) {
        int n = wy + j * 16;
        int p = __builtin_amdgcn_cvt_pk_fp8_f32(
            scale * t[4 * wx + 0][n], scale * t[4 * wx + 1][n], 0, false);
        p = __builtin_amdgcn_cvt_pk_fp8_f32(
            scale * t[4 * wx + 2][n], scale * t[4 * wx + 3][n], p, true);
        *(int*)(out + (long)(n0 + n) * ldo + m0 + 4 * wx) = p;
    }
}

// ---------------------------------------------------------------------------
// Batched bf16 transpose (for V): out[n][m] = in[m][n]. Tile 32x32.
// ---------------------------------------------------------------------------
__global__ __launch_bounds__(256)
void transpose_k(const bf16* __restrict__ in, bf16* __restrict__ out,
                 int ldi, int ldo, long sIo, long sIi, long sOo, long sOi, int zInner)
{
    int z = blockIdx.z;
    in  += (long)(z / zInner) * sIo + (long)(z % zInner) * sIi;
    out += (long)(z / zInner) * sOo + (long)(z % zInner) * sOi;
    __shared__ bf16 t[32][33];
    int tx = threadIdx.x & 31, ty = threadIdx.x >> 5;
    int n0 = blockIdx.x * 32, m0 = blockIdx.y * 32;
#pragma unroll
    for (int i = 0; i < 4; ++i)
        t[ty + i * 8][tx] = in[(long)(m0 + ty + i * 8) * ldi + n0 + tx];
    __syncthreads();
#pragma unroll
    for (int i = 0; i < 4; ++i)
        out[(long)(n0 + ty + i * 8) * ldo + m0 + tx] = t[tx][ty + i * 8];
}

// f32 -> bf16 elementwise (for image_embeds). 4 elems/thread.
__global__ __launch_bounds__(256)
void cvt_k(const float* __restrict__ in, bf16* __restrict__ out)
{
    int i = (blockIdx.x * 256 + threadIdx.x) * 4;
    float4 v = *(const float4*)(in + i);
    out[i + 0] = (bf16)v.x;
    out[i + 1] = (bf16)v.y;
    out[i + 2] = (bf16)v.z;
    out[i + 3] = (bf16)v.w;
}

// ---------------------------------------------------------------------------
// Workspace layout (MiB offsets), peak 176 MiB:
//   0-32   : WqT(0) WkT(8) WvT(16) WoT(24)  -> later W1T(0-32)
//   32-48  : xln        -> later W2T8 (fp8, 16MB)
//   48-64  : q/attn_out
//   64-68  : kbuf   68-72: vbuf   72-76: vt   76-80: imgb
//   80-144 : sc (scores bf16 64MB -> P) ; h1fp8 (fp8 32MB @80-112)
//   144-176: x2 (f32)
// h1 tail garbage reads: past xln -> q region; past W1T -> xln region (both
// allocated, values never consumed). gemm_fp8 K=8192 exact, no tail.
// ---------------------------------------------------------------------------
extern "C" void kernel_launch(void* const* d_in, const int* in_sizes, int n_in,
                              void* d_out, int out_size, void* d_ws, size_t ws_size,
                              hipStream_t stream)
{
    const float* hidden = (const float*)d_in[0];  // (2,2048,2048) f32
    const float* image  = (const float*)d_in[1];  // (2,8,64,2048) f32
    const int*   media  = (const int*)d_in[2];    // (2,2048)
    const float* Wq = (const float*)d_in[3];
    const float* Wk = (const float*)d_in[4];
    const float* Wv = (const float*)d_in[5];
    const float* Wo = (const float*)d_in[6];
    const float* lag = (const float*)d_in[7];
    const float* lab = (const float*)d_in[8];
    const float* lfg = (const float*)d_in[9];
    const float* lfb = (const float*)d_in[10];
    const float* W1 = (const float*)d_in[11];     // (2048, 8192)
    const float* b1 = (const float*)d_in[12];
    const float* W2 = (const float*)d_in[13];     // (8192, 2048)
    const float* b2 = (const float*)d_in[14];
    const float* ga = (const float*)d_in[15];
    const float* gf = (const float*)d_in[16];
    float* out = (float*)d_out;

    char* ws = (char*)d_ws;
    const size_t MB = 1ull << 20;
    bf16* WqT  = (bf16*)(ws + 0);
    bf16* WkT  = (bf16*)(ws + 8 * MB);
    bf16* WvT  = (bf16*)(ws + 16 * MB);
    bf16* WoT  = (bf16*)(ws + 24 * MB);
    bf16* W1T  = (bf16*)(ws + 0);            // reuses Wq..Wo region after attn
    uint8_t* W2T8 = (uint8_t*)(ws + 32 * MB);// fp8, reuses xln after ln2 staged
    bf16* xln  = (bf16*)(ws + 32 * MB);
    bf16* q    = (bf16*)(ws + 48 * MB);
    bf16* kbuf = (bf16*)(ws + 64 * MB);
    bf16* vbuf = (bf16*)(ws + 68 * MB);
    bf16* vt   = (bf16*)(ws + 72 * MB);
    bf16* imgb = (bf16*)(ws + 76 * MB);
    bf16* sc   = (bf16*)(ws + 80 * MB);
    uint8_t* h1f8 = (uint8_t*)(ws + 80 * MB);// fp8 h1, over dead scores
    float* x2  = (float*)(ws + 144 * MB);

    const float SCALE = 0.08838834764831845f; // 128^-0.5
    const float A8 = 8.f, B8 = 64.f;          // fp8 scales (h1, W2)
    dim3 blk(256);

    // f32 -> bf16 conversions / transposes
    transpose_cvt<<<dim3(64, 32, 1), blk, 0, stream>>>(Wq, WqT, 2048, 2048);
    transpose_cvt<<<dim3(64, 32, 1), blk, 0, stream>>>(Wk, WkT, 2048, 2048);
    transpose_cvt<<<dim3(64, 32, 1), blk, 0, stream>>>(Wv, WvT, 2048, 2048);
    transpose_cvt<<<dim3(64, 32, 1), blk, 0, stream>>>(Wo, WoT, 2048, 2048);
    cvt_k<<<2048, blk, 0, stream>>>(image, imgb);   // 2*512*2048 elems

    // x = LN(hidden)  (f32 in, bf16 out)
    ln_k<<<4096, blk, 0, stream>>>(hidden, lag, lab, xln);

    // q = x @ Wq   (M=4096, N=2048, K=2048)
    gemm_bt<0, bf16><<<dim3(16, 32, 1), blk, 0, stream>>>(
        xln, WqT, q, 2048, 2048, 2048, 2048, 0, 0, 0, 0, 0, 0, 1, 1.f,
        nullptr, nullptr, nullptr);

    // k, v = image @ {Wk, Wv}  (M=1024, N=2048, K=2048; zi=0 -> k, zi=1 -> v)
    gemm_bt<0, bf16><<<dim3(16, 8, 2), blk, 0, stream>>>(
        imgb, WkT, kbuf, 2048, 2048, 2048, 2048,
        0, 0, 0, 4194304, 0, 2097152, 2, 1.f,
        nullptr, nullptr, nullptr);

    // vt[b][h][d][kv] = v[b][kv][h*128+d]
    transpose_k<<<dim3(4, 16, 32), blk, 0, stream>>>(
        vbuf, vt, 2048, 512, 1048576, 128, 1048576, 65536, 16);

    // scores[b][h][s][kv] = SCALE * q_bh @ k_bh^T  (M=2048, N=512, K=128)
    gemm_bt<0, bf16><<<dim3(4, 16, 32), blk, 0, stream>>>(
        q, kbuf, sc, 128, 2048, 2048, 512,
        4194304, 128, 1048576, 128, 16777216, 1048576, 16, SCALE,
        nullptr, nullptr, nullptr);

    // softmax over kv (in place)
    softmax512<<<16384, blk, 0, stream>>>(sc);

    // attn_out[b][s][h*128+d] = P_bh @ vt_bh^T  (M=2048, N=128, K=512)
    gemm_bt<0, bf16><<<dim3(1, 16, 32), blk, 0, stream>>>(
        sc, vt, q, 512, 512, 512, 2048,
        16777216, 1048576, 1048576, 65536, 4194304, 128, 16, 1.f,
        nullptr, nullptr, nullptr);

    // x2 = hidden + tanh(ga) * (attn_out @ Wo) * mask   (f32 out)
    gemm_bt<2, float><<<dim3(16, 32, 1), blk, 0, stream>>>(
        q, WoT, x2, 2048, 2048, 2048, 2048, 0, 0, 0, 0, 0, 0, 1, 1.f,
        hidden, ga, media);

    // FFN weights (reuse dead regions)
    transpose_cvt<<<dim3(256, 32, 1), blk, 0, stream>>>(W1, W1T, 8192, 2048);

    // ln2 = LN(x2)
    ln_k<<<4096, blk, 0, stream>>>(x2, lfg, lfb, xln);

    // h1f8 = fp8(8 * gelu(ln2 @ W1 + b1))  (M=4096, N=8192, K=2048)
    gemm256_h1<<<dim3(32, 16, 1), dim3(512), 0, stream>>>(
        xln, W1T, h1f8, 2048, 2048, 2048, 8192, b1);

    // W2T8 = fp8(64 * W2^T) after h1 (xln dead now)
    transpose_cvt8<<<dim3(64, 128, 1), blk, 0, stream>>>(W2, W2T8, 2048, 8192, B8);

    // out = x2 + tanh(gf) * (h1 @ W2 + b2)  — fp8 GEMM, alpha undoes scales
    gemm_fp8<<<dim3(16, 32, 1), blk, 0, stream>>>(
        h1f8, W2T8, out, 8192, 8192, 8192, 2048, 1.f / (A8 * B8),
        x2, b2, gf);
}

// Round 9
// 797.195 us; speedup vs baseline: 1.3883x; 1.1496x over previous
//
#include <hip/hip_runtime.h>
#include <math.h>
#include <stdint.h>

typedef __bf16 bf16;
typedef __bf16 bf16x8 __attribute__((ext_vector_type(8)));
typedef __bf16 bf16x4 __attribute__((ext_vector_type(4)));
typedef float f32x4 __attribute__((ext_vector_type(4)));

#define DEV __device__ __forceinline__

// async global->LDS, 16B per lane. LDS dest must be wave-uniform base + lane*16.
DEV void g2l16(void* lds, const void* g) {
    __builtin_amdgcn_global_load_lds(
        (const __attribute__((address_space(1))) uint32_t*)g,
        (__attribute__((address_space(3))) uint32_t*)lds,
        16, 0, 0);
}

// Fast gelu: x * sigmoid(1.5957691216*(x + 0.044715 x^3)).
DEV float gelu_fast(float x) {
    float u = -1.5957691216f * __builtin_fmaf(0.044715f * x, x * x, x);
    return x * __builtin_amdgcn_rcpf(1.f + __expf(u));
}

// f32 -> OCP e4m3 byte (saturating hardware convert).
DEV uint8_t to_fp8(float x) {
    return (uint8_t)(__builtin_amdgcn_cvt_pk_fp8_f32(x, x, 0, false) & 0xff);
}

// XCD-chunked block swizzle (T1). Bijective iff nwg % 8 == 0 (guarded).
// Measured r5: W2 FETCH -33%, -8% dur.
DEV void xcd_swizzle(int& bx, int& by, int& bz) {
    int gx = gridDim.x, gy = gridDim.y, gz = gridDim.z;
    int nwg = gx * gy * gz;
    if (nwg & 7) return;
    long flat = ((long)bz * gy + by) * gx + bx;
    long q = nwg >> 3;
    long sw = (flat & 7) * q + (flat >> 3);
    bx = (int)(sw % gx);
    long t = sw / gx;
    by = (int)(t % gy);
    bz = (int)(t / gy);
}

// ---------------------------------------------------------------------------
// bf16 GEMM (128x128, BK=64): for the attention ops (short-K, bf16 operands).
// EPI: 0 plain*alpha (TC out); 4 fp8 out = e4m3(16*v).
// ---------------------------------------------------------------------------
template <int EPI, typename TC>
__global__ __launch_bounds__(256)
void gemm_bt(const bf16* __restrict__ A, const bf16* __restrict__ Bt, TC* __restrict__ C,
             int K, int lda, int ldb, int ldc,
             long sAo, long sAi, long sBo, long sBi, long sCo, long sCi, int zInner,
             float alpha)
{
    int bx = blockIdx.x, by = blockIdx.y, bz = blockIdx.z;
    xcd_swizzle(bx, by, bz);

    int zo = bz / zInner, zi = bz % zInner;
    A  += (long)zo * sAo + (long)zi * sAi;
    Bt += (long)zo * sBo + (long)zi * sBi;
    long cOff = (long)zo * sCo + (long)zi * sCi;

    int tileN = bx * 128, tileM = by * 128;

    __shared__ bf16 As[8192];  // [kc][row][8]
    __shared__ bf16 Bs[8192];

    int tid = threadIdx.x;
    int wave = tid >> 6, lane = tid & 63, quad = lane >> 4, l15 = lane & 15;
    int wm = (wave >> 1) * 64, wn = (wave & 1) * 64;

    f32x4 acc[4][4] = {};

    for (int k0 = 0; k0 < K; k0 += 64) {
#pragma unroll
        for (int r = 0; r < 4; ++r) {
            int c = r * 256 + tid;
            int kc = c >> 7, row = c & 127;
            g2l16(&As[c * 8], A + (long)(tileM + row) * lda + (k0 + kc * 8));
            g2l16(&Bs[c * 8], Bt + (long)(tileN + row) * ldb + (k0 + kc * 8));
        }
        __syncthreads();
#pragma unroll
        for (int ks = 0; ks < 2; ++ks) {
            bf16x8 af[4], bq[4];
#pragma unroll
            for (int i = 0; i < 4; ++i) {
                af[i] = *(const bf16x8*)&As[((ks * 4 + quad) * 128 + wm + i * 16 + l15) * 8];
                bq[i] = *(const bf16x8*)&Bs[((ks * 4 + quad) * 128 + wn + i * 16 + l15) * 8];
            }
#pragma unroll
            for (int mi = 0; mi < 4; ++mi)
#pragma unroll
                for (int ni = 0; ni < 4; ++ni)
                    acc[mi][ni] = __builtin_amdgcn_mfma_f32_16x16x32_bf16(
                        af[mi], bq[ni], acc[mi][ni], 0, 0, 0);
        }
        __syncthreads();
    }

#pragma unroll
    for (int mi = 0; mi < 4; ++mi) {
#pragma unroll
        for (int r = 0; r < 4; ++r) {
            int gm = tileM + wm + mi * 16 + quad * 4 + r;
#pragma unroll
            for (int ni = 0; ni < 4; ++ni) {
                int gn = tileN + wn + ni * 16 + l15;
                float v = acc[mi][ni][r] * alpha;
                if (EPI == 0) {
                    C[cOff + (long)gm * ldc + gn] = (TC)v;
                } else {
                    C[cOff + (long)gm * ldc + gn] = (TC)to_fp8(16.f * v);
                }
            }
        }
    }
}

// ---------------------------------------------------------------------------
// fp8 (e4m3) GEMM, 128x128 tile, BK=128. HW-validated layout (r8) + 947 TF
// measured: staged bytes per K-tile = bf16 kernel's 32KB but 2x FLOP.
// Fragment map (mirrors verified bf16 16x16x32): lane's 8 k-bytes for 32-k
// step ks live in granule kc16 = ks*2 + (quad>>1), byte off (quad&1)*8.
// EPI: 0 plain*alpha (TC out); 1 fp8(8*gelu(v+bias)); 2 resid+tanh(g)*v*mask;
//      3 resid+tanh(g)*(v+bias)
// ---------------------------------------------------------------------------
template <int EPI, typename TC>
__global__ __launch_bounds__(256)
void gemm_fp8(const uint8_t* __restrict__ A, const uint8_t* __restrict__ Bt,
              TC* __restrict__ C, int K, int lda, int ldb, int ldc, float alpha,
              const float* __restrict__ resid,
              const float* __restrict__ bias,
              const float* __restrict__ gamma,
              const int* __restrict__ mask)
{
    int bx = blockIdx.x, by = blockIdx.y, bz = blockIdx.z;
    xcd_swizzle(bx, by, bz);

    int tileN = bx * 128, tileM = by * 128;

    __shared__ uint8_t As[16384];  // [kc16 0..7][row 0..127][16]
    __shared__ uint8_t Bs[16384];

    int tid = threadIdx.x;
    int wave = tid >> 6, lane = tid & 63, quad = lane >> 4, l15 = lane & 15;
    int wm = (wave >> 1) * 64, wn = (wave & 1) * 64;

    f32x4 acc[4][4] = {};

    for (int k0 = 0; k0 < K; k0 += 128) {
#pragma unroll
        for (int r = 0; r < 4; ++r) {
            int c = r * 256 + tid;              // c = kc16*128 + row
            int kc = c >> 7, row = c & 127;
            g2l16(&As[c * 16], A + (long)(tileM + row) * lda + (k0 + kc * 16));
            g2l16(&Bs[c * 16], Bt + (long)(tileN + row) * ldb + (k0 + kc * 16));
        }
        __syncthreads();
#pragma unroll
        for (int ks = 0; ks < 4; ++ks) {        // 4 x 32-k MFMA steps
            int kc16 = ks * 2 + (quad >> 1);
            int boff = (quad & 1) * 8;
            long af[4], bq[4];
#pragma unroll
            for (int i = 0; i < 4; ++i) {
                af[i] = *(const long*)&As[(kc16 * 128 + wm + i * 16 + l15) * 16 + boff];
                bq[i] = *(const long*)&Bs[(kc16 * 128 + wn + i * 16 + l15) * 16 + boff];
            }
#pragma unroll
            for (int mi = 0; mi < 4; ++mi)
#pragma unroll
                for (int ni = 0; ni < 4; ++ni)
                    acc[mi][ni] = __builtin_amdgcn_mfma_f32_16x16x32_fp8_fp8(
                        af[mi], bq[ni], acc[mi][ni], 0, 0, 0);
        }
        __syncthreads();
    }

    float gscale = 0.f;
    if (EPI == 2 || EPI == 3) gscale = tanhf(gamma[0]);
    float bb[4] = {};
    if (EPI == 1 || EPI == 3) {
#pragma unroll
        for (int ni = 0; ni < 4; ++ni)
            bb[ni] = bias[tileN + wn + ni * 16 + l15];
    }

#pragma unroll
    for (int mi = 0; mi < 4; ++mi) {
#pragma unroll
        for (int r = 0; r < 4; ++r) {
            int gm = tileM + wm + mi * 16 + quad * 4 + r;
            float rowmask = 1.f;
            if (EPI == 2) rowmask = mask[gm] ? 1.f : 0.f;
#pragma unroll
            for (int ni = 0; ni < 4; ++ni) {
                int gn = tileN + wn + ni * 16 + l15;
                float v = acc[mi][ni][r] * alpha;
                if (EPI == 0) {
                    C[(long)gm * ldc + gn] = (TC)v;
                } else if (EPI == 1) {
                    C[(long)gm * ldc + gn] = (TC)to_fp8(8.f * gelu_fast(v + bb[ni]));
                } else if (EPI == 2) {
                    float h = resid[(long)gm * ldc + gn];
                    C[(long)gm * ldc + gn] = (TC)(h + gscale * v * rowmask);
                } else {
                    float h = resid[(long)gm * ldc + gn];
                    C[(long)gm * ldc + gn] = (TC)(h + gscale * (v + bb[ni]));
                }
            }
        }
    }
}

// ---------------------------------------------------------------------------
// LayerNorm over rows of 2048 (f32 in, f32 params, fp8 e4m3 out x16).
// One row/block; packed 8B stores via v_cvt_pk_fp8_f32.
// ---------------------------------------------------------------------------
__global__ __launch_bounds__(256)
void ln8_k(const float* __restrict__ x, const float* __restrict__ g, const float* __restrict__ b,
           uint8_t* __restrict__ out)
{
    long row = blockIdx.x;
    int tid = threadIdx.x;
    int wave = tid >> 6, lane = tid & 63;
    const float* px = x + row * 2048 + tid * 8;

    float4 a = *(const float4*)px;
    float4 c = *(const float4*)(px + 4);
    float f[8] = {a.x, a.y, a.z, a.w, c.x, c.y, c.z, c.w};

    float s = 0.f, s2 = 0.f;
#pragma unroll
    for (int j = 0; j < 8; ++j) { s += f[j]; s2 += f[j] * f[j]; }
    for (int o = 32; o; o >>= 1) { s += __shfl_xor(s, o, 64); s2 += __shfl_xor(s2, o, 64); }

    __shared__ float red[8];
    if (lane == 0) { red[wave] = s; red[4 + wave] = s2; }
    __syncthreads();
    s  = red[0] + red[1] + red[2] + red[3];
    s2 = red[4] + red[5] + red[6] + red[7];

    float mean = s * (1.f / 2048.f);
    float var  = s2 * (1.f / 2048.f) - mean * mean;
    float rstd = rsqrtf(var + 1e-5f);

    int col = tid * 8;
    float o[8];
#pragma unroll
    for (int j = 0; j < 8; ++j)
        o[j] = 16.f * ((f[j] - mean) * rstd * g[col + j] + b[col + j]);
    int p0 = __builtin_amdgcn_cvt_pk_fp8_f32(o[0], o[1], 0, false);
    p0     = __builtin_amdgcn_cvt_pk_fp8_f32(o[2], o[3], p0, true);
    int p1 = __builtin_amdgcn_cvt_pk_fp8_f32(o[4], o[5], 0, false);
    p1     = __builtin_amdgcn_cvt_pk_fp8_f32(o[6], o[7], p1, true);
    *(int2*)(out + row * 2048 + tid * 8) = make_int2(p0, p1);
}

// ---------------------------------------------------------------------------
// Row softmax over 512 (in-place, bf16). One wave per row, 4 rows per block.
// ---------------------------------------------------------------------------
__global__ __launch_bounds__(256)
void softmax512(bf16* __restrict__ s)
{
    long row = (long)blockIdx.x * 4 + (threadIdx.x >> 6);
    int lane = threadIdx.x & 63;
    bf16* p = s + row * 512 + lane * 8;
    bf16x8 v = *(const bf16x8*)p;
    float f[8], mx = -1e30f;
#pragma unroll
    for (int j = 0; j < 8; ++j) { f[j] = (float)v[j]; mx = fmaxf(mx, f[j]); }
    for (int o = 32; o; o >>= 1) mx = fmaxf(mx, __shfl_xor(mx, o, 64));
    float sum = 0.f;
#pragma unroll
    for (int j = 0; j < 8; ++j) { f[j] = __expf(f[j] - mx); sum += f[j]; }
    for (int o = 32; o; o >>= 1) sum += __shfl_xor(sum, o, 64);
    float r = 1.f / sum;
    bf16x8 o8;
#pragma unroll
    for (int j = 0; j < 8; ++j) o8[j] = (bf16)(f[j] * r);
    *(bf16x8*)p = o8;
}

// ---------------------------------------------------------------------------
// Transpose f32 -> bf16: out[n][m] = (bf16)in[m][n]. Tile 64m x 32n, 256 thr.
// ---------------------------------------------------------------------------
__global__ __launch_bounds__(256)
void transpose_cvt(const float* __restrict__ in, bf16* __restrict__ out, int ldi, int ldo)
{
    __shared__ float t[64][33];
    int tx = threadIdx.x & 31, ty = threadIdx.x >> 5;
    int n0 = blockIdx.x * 32, m0 = blockIdx.y * 64;
#pragma unroll
    for (int i = 0; i < 8; ++i)
        t[ty + i * 8][tx] = in[(long)(m0 + ty + i * 8) * ldi + n0 + tx];
    __syncthreads();
    int wx = threadIdx.x & 15, wy = threadIdx.x >> 4;
#pragma unroll
    for (int j = 0; j < 2; ++j) {
        int n = wy + j * 16;
        bf16x4 v;
        v[0] = (bf16)t[4 * wx + 0][n];
        v[1] = (bf16)t[4 * wx + 1][n];
        v[2] = (bf16)t[4 * wx + 2][n];
        v[3] = (bf16)t[4 * wx + 3][n];
        *(bf16x4*)(out + (long)(n0 + n) * ldo + m0 + 4 * wx) = v;
    }
}

// ---------------------------------------------------------------------------
// Transpose f32 -> fp8 e4m3 (x scale): out[n][m] = fp8(scale*in[m][n]).
// Tile 64m x 32n; 4-byte packed stores via v_cvt_pk_fp8_f32. (HW-validated r8)
// ---------------------------------------------------------------------------
__global__ __launch_bounds__(256)
void transpose_cvt8(const float* __restrict__ in, uint8_t* __restrict__ out,
                    int ldi, int ldo, float scale)
{
    __shared__ float t[64][33];
    int tx = threadIdx.x & 31, ty = threadIdx.x >> 5;
    int n0 = blockIdx.x * 32, m0 = blockIdx.y * 64;
#pragma unroll
    for (int i = 0; i < 8; ++i)
        t[ty + i * 8][tx] = in[(long)(m0 + ty + i * 8) * ldi + n0 + tx];
    __syncthreads();
    int wx = threadIdx.x & 15, wy = threadIdx.x >> 4;
#pragma unroll
    for (int j = 0; j < 2; ++j) {
        int n = wy + j * 16;
        int p = __builtin_amdgcn_cvt_pk_fp8_f32(
            scale * t[4 * wx + 0][n], scale * t[4 * wx + 1][n], 0, false);
        p = __builtin_amdgcn_cvt_pk_fp8_f32(
            scale * t[4 * wx + 2][n], scale * t[4 * wx + 3][n], p, true);
        *(int*)(out + (long)(n0 + n) * ldo + m0 + 4 * wx) = p;
    }
}

// ---------------------------------------------------------------------------
// Batched bf16 transpose (for V): out[n][m] = in[m][n]. Tile 32x32.
// ---------------------------------------------------------------------------
__global__ __launch_bounds__(256)
void transpose_k(const bf16* __restrict__ in, bf16* __restrict__ out,
                 int ldi, int ldo, long sIo, long sIi, long sOo, long sOi, int zInner)
{
    int z = blockIdx.z;
    in  += (long)(z / zInner) * sIo + (long)(z % zInner) * sIi;
    out += (long)(z / zInner) * sOo + (long)(z % zInner) * sOi;
    __shared__ bf16 t[32][33];
    int tx = threadIdx.x & 31, ty = threadIdx.x >> 5;
    int n0 = blockIdx.x * 32, m0 = blockIdx.y * 32;
#pragma unroll
    for (int i = 0; i < 4; ++i)
        t[ty + i * 8][tx] = in[(long)(m0 + ty + i * 8) * ldi + n0 + tx];
    __syncthreads();
#pragma unroll
    for (int i = 0; i < 4; ++i)
        out[(long)(n0 + ty + i * 8) * ldo + m0 + tx] = t[tx][ty + i * 8];
}

// f32 -> bf16 elementwise (for image_embeds). 4 elems/thread.
__global__ __launch_bounds__(256)
void cvt_k(const float* __restrict__ in, bf16* __restrict__ out)
{
    int i = (blockIdx.x * 256 + threadIdx.x) * 4;
    float4 v = *(const float4*)(in + i);
    out[i + 0] = (bf16)v.x;
    out[i + 1] = (bf16)v.y;
    out[i + 2] = (bf16)v.z;
    out[i + 3] = (bf16)v.w;
}

// ---------------------------------------------------------------------------
// Workspace layout (MiB offsets), peak 176 MiB:
//   0-4    : WqT8        -> later W1T8 (0-16)
//   4-8    : WoT8
//   8-16   : WkT (bf16)
//   16-24  : WvT (bf16)
//   32-40  : xln8        -> later W2T8 (32-48)
//   48-64  : q (bf16 16MB) -> ao8 (48-56) -> ln2_8 (48-56)
//   64-68  : kbuf  68-72: vbuf  72-76: vt  76-80: imgb
//   80-144 : sc (scores bf16 64MB -> P) -> h1f8 (fp8 32MB @80-112)
//   144-176: x2 (f32)
// Lifetimes: WqT8 dead after q; q dead after scores; ao8 dead after Wo;
// xln8 dead after q; sc dead after PV; W1T8 written after Wo (Wq/Wk dead).
// All fp8 GEMMs have K % 128 == 0: no tail reads.
// ---------------------------------------------------------------------------
extern "C" void kernel_launch(void* const* d_in, const int* in_sizes, int n_in,
                              void* d_out, int out_size, void* d_ws, size_t ws_size,
                              hipStream_t stream)
{
    const float* hidden = (const float*)d_in[0];  // (2,2048,2048) f32
    const float* image  = (const float*)d_in[1];  // (2,8,64,2048) f32
    const int*   media  = (const int*)d_in[2];    // (2,2048)
    const float* Wq = (const float*)d_in[3];
    const float* Wk = (const float*)d_in[4];
    const float* Wv = (const float*)d_in[5];
    const float* Wo = (const float*)d_in[6];
    const float* lag = (const float*)d_in[7];
    const float* lab = (const float*)d_in[8];
    const float* lfg = (const float*)d_in[9];
    const float* lfb = (const float*)d_in[10];
    const float* W1 = (const float*)d_in[11];     // (2048, 8192)
    const float* b1 = (const float*)d_in[12];
    const float* W2 = (const float*)d_in[13];     // (8192, 2048)
    const float* b2 = (const float*)d_in[14];
    const float* ga = (const float*)d_in[15];
    const float* gf = (const float*)d_in[16];
    float* out = (float*)d_out;

    char* ws = (char*)d_ws;
    const size_t MB = 1ull << 20;
    uint8_t* WqT8 = (uint8_t*)(ws + 0);
    uint8_t* WoT8 = (uint8_t*)(ws + 4 * MB);
    bf16*    WkT  = (bf16*)(ws + 8 * MB);
    bf16*    WvT  = (bf16*)(ws + 16 * MB);
    uint8_t* W1T8 = (uint8_t*)(ws + 0);          // after attn (Wq/Wk dead)
    uint8_t* xln8 = (uint8_t*)(ws + 32 * MB);
    uint8_t* W2T8 = (uint8_t*)(ws + 32 * MB);    // after q (xln8 dead)
    bf16*    q    = (bf16*)(ws + 48 * MB);
    uint8_t* ao8  = (uint8_t*)(ws + 48 * MB);    // after scores (q dead)
    uint8_t* ln28 = (uint8_t*)(ws + 48 * MB);    // after Wo (ao8 dead)
    bf16*    kbuf = (bf16*)(ws + 64 * MB);
    bf16*    vbuf = (bf16*)(ws + 68 * MB);
    bf16*    vt   = (bf16*)(ws + 72 * MB);
    bf16*    imgb = (bf16*)(ws + 76 * MB);
    bf16*    sc   = (bf16*)(ws + 80 * MB);
    uint8_t* h1f8 = (uint8_t*)(ws + 80 * MB);    // after PV (sc dead)
    float*   x2   = (float*)(ws + 144 * MB);

    const float SCALE = 0.08838834764831845f; // 128^-0.5
    const float INV1024 = 1.f / 1024.f;       // undo 16 (act) * 64 (weight)
    const float INV512  = 1.f / 512.f;        // undo 8 (h1) * 64 (W2)
    dim3 blk(256);

    // weight transposes (fp8 for the big GEMMs, bf16 for k/v projection)
    transpose_cvt8<<<dim3(64, 32, 1), blk, 0, stream>>>(Wq, WqT8, 2048, 2048, 64.f);
    transpose_cvt <<<dim3(64, 32, 1), blk, 0, stream>>>(Wk, WkT, 2048, 2048);
    transpose_cvt <<<dim3(64, 32, 1), blk, 0, stream>>>(Wv, WvT, 2048, 2048);
    transpose_cvt8<<<dim3(64, 32, 1), blk, 0, stream>>>(Wo, WoT8, 2048, 2048, 64.f);
    cvt_k<<<2048, blk, 0, stream>>>(image, imgb);   // 2*512*2048 elems

    // xln8 = fp8(16 * LN(hidden))
    ln8_k<<<4096, blk, 0, stream>>>(hidden, lag, lab, xln8);

    // q = xln @ Wq   (M=4096, N=2048, K=2048) — fp8, bf16 out
    gemm_fp8<0, bf16><<<dim3(16, 32, 1), blk, 0, stream>>>(
        xln8, WqT8, q, 2048, 2048, 2048, 2048, INV1024,
        nullptr, nullptr, nullptr, nullptr);

    // k, v = image @ {Wk, Wv}  (M=1024, N=2048, K=2048; zi=0 -> k, zi=1 -> v)
    gemm_bt<0, bf16><<<dim3(16, 8, 2), blk, 0, stream>>>(
        imgb, WkT, kbuf, 2048, 2048, 2048, 2048,
        0, 0, 0, 4194304, 0, 2097152, 2, 1.f);

    // vt[b][h][d][kv] = v[b][kv][h*128+d]
    transpose_k<<<dim3(4, 16, 32), blk, 0, stream>>>(
        vbuf, vt, 2048, 512, 1048576, 128, 1048576, 65536, 16);

    // scores[b][h][s][kv] = SCALE * q_bh @ k_bh^T  (M=2048, N=512, K=128)
    gemm_bt<0, bf16><<<dim3(4, 16, 32), blk, 0, stream>>>(
        q, kbuf, sc, 128, 2048, 2048, 512,
        4194304, 128, 1048576, 128, 16777216, 1048576, 16, SCALE);

    // softmax over kv (in place)
    softmax512<<<16384, blk, 0, stream>>>(sc);

    // ao8 = fp8(16 * P_bh @ vt_bh^T)  (M=2048, N=128, K=512) — overwrites q
    gemm_bt<4, uint8_t><<<dim3(1, 16, 32), blk, 0, stream>>>(
        sc, vt, ao8, 512, 512, 512, 2048,
        16777216, 1048576, 1048576, 65536, 4194304, 128, 16, 1.f);

    // x2 = hidden + tanh(ga) * (attn_out @ Wo) * mask   (fp8 GEMM, f32 out)
    gemm_fp8<2, float><<<dim3(16, 32, 1), blk, 0, stream>>>(
        ao8, WoT8, x2, 2048, 2048, 2048, 2048, INV1024,
        hidden, nullptr, ga, media);

    // W1T8 = fp8(64 * W1^T)  (Wq/Wk regions dead)
    transpose_cvt8<<<dim3(256, 32, 1), blk, 0, stream>>>(W1, W1T8, 8192, 2048, 64.f);

    // ln2_8 = fp8(16 * LN(x2))  (ao8 dead)
    ln8_k<<<4096, blk, 0, stream>>>(x2, lfg, lfb, ln28);

    // h1f8 = fp8(8 * gelu(ln2 @ W1 + b1))  (M=4096, N=8192, K=2048)
    gemm_fp8<1, uint8_t><<<dim3(64, 32, 1), blk, 0, stream>>>(
        ln28, W1T8, h1f8, 2048, 2048, 2048, 8192, INV1024,
        nullptr, b1, nullptr, nullptr);

    // W2T8 = fp8(64 * W2^T)  (xln8 dead)
    transpose_cvt8<<<dim3(64, 128, 1), blk, 0, stream>>>(W2, W2T8, 2048, 8192, 64.f);

    // out = x2 + tanh(gf) * (h1 @ W2 + b2)  (M=4096, N=2048, K=8192)
    gemm_fp8<3, float><<<dim3(16, 32, 1), blk, 0, stream>>>(
        h1f8, W2T8, out, 8192, 8192, 8192, 2048, INV512,
        x2, b2, gf, nullptr);
}